// Round 12
// baseline (1119.007 us; speedup 1.0000x reference)
//
#include <hip/hip_runtime.h>
#include <hip/hip_fp16.h>

#define N_NODES 100000
#define N_EDGES 1600000
#define TS      128
#define NTILE   ((N_NODES + TS - 1) / TS)            // 782
#define NGRP    (NTILE * 8)                          // 6256 (tile, octant) groups
#define E_PAD2  (N_EDGES + NGRP * 64 + 256)          // 2000640, mult of 256
#define GRID_E2 (E_PAD2 / 256)

typedef _Float16 f16x8 __attribute__((ext_vector_type(8)));
typedef float    f32x4 __attribute__((ext_vector_type(4)));

// ===================================================================
// helpers
// ===================================================================

__device__ __forceinline__ void pseudo_to_of(float p0, float p1, float p2,
                                             int& oct, float& fr0, float& fr1, float& fr2) {
    float v0 = p0 * 2.0f, v1 = p1 * 2.0f, v2 = p2 * 2.0f;
    int i0 = v0 >= 1.0f, i1 = v1 >= 1.0f, i2 = v2 >= 1.0f;
    fr0 = v0 - (float)i0; fr1 = v1 - (float)i1; fr2 = v2 - (float)i2;
    oct = i0 + 2 * i1 + 4 * i2;
}

template<int Fin>
__device__ __forceinline__ void loadanyT(const float* __restrict__ hp, float* x) {
    if constexpr (Fin % 4 == 0) {
        const float4* xv = reinterpret_cast<const float4*>(hp);
        #pragma unroll
        for (int f = 0; f < Fin / 4; ++f) {
            float4 t = xv[f];
            x[4*f+0] = t.x; x[4*f+1] = t.y; x[4*f+2] = t.z; x[4*f+3] = t.w;
        }
    } else {
        #pragma unroll
        for (int f = 0; f < Fin; ++f) x[f] = hp[f];
    }
}

template<int Fin>
__device__ __forceinline__ void loadanyT(const __half* __restrict__ hp, float* x) {
    if constexpr (Fin % 8 == 0) {
        #pragma unroll
        for (int r = 0; r < Fin / 8; ++r) {
            union { uint4 v; __half2 h2[4]; } u;
            u.v = ((const uint4*)hp)[r];
            #pragma unroll
            for (int q = 0; q < 4; ++q) {
                float2 f = __half22float2(u.h2[q]);
                x[r*8 + 2*q]     = f.x;
                x[r*8 + 2*q + 1] = f.y;
            }
        }
    } else {
        #pragma unroll
        for (int f = 0; f < Fin; ++f) x[f] = __half2float(hp[f]);
    }
}

template<int CH>
__device__ __forceinline__ void storeanyT(float* __restrict__ p, const float* z) {
    if constexpr (CH % 4 == 0) {
        #pragma unroll
        for (int o = 0; o < CH / 4; ++o) {
            float4 t; t.x = z[4*o]; t.y = z[4*o+1]; t.z = z[4*o+2]; t.w = z[4*o+3];
            ((float4*)p)[o] = t;
        }
    } else if constexpr (CH % 2 == 0) {
        #pragma unroll
        for (int o = 0; o < CH / 2; ++o) {
            float2 t; t.x = z[2*o]; t.y = z[2*o+1];
            ((float2*)p)[o] = t;
        }
    } else {
        #pragma unroll
        for (int o = 0; o < CH; ++o) p[o] = z[o];
    }
}

template<int CH>
__device__ __forceinline__ void storeanyT(__half* __restrict__ p, const float* z) {
    if constexpr (CH % 8 == 0) {
        #pragma unroll
        for (int q = 0; q < CH / 8; ++q) {
            union { uint4 v; __half2 h2[4]; } u;
            #pragma unroll
            for (int r = 0; r < 4; ++r)
                u.h2[r] = __floats2half2_rn(z[q*8 + 2*r], z[q*8 + 2*r + 1]);
            ((uint4*)p)[q] = u.v;
        }
    } else if constexpr (CH % 4 == 0) {
        #pragma unroll
        for (int q = 0; q < CH / 4; ++q) {
            union { uint2 v; __half2 h2[2]; } u;
            u.h2[0] = __floats2half2_rn(z[4*q],     z[4*q + 1]);
            u.h2[1] = __floats2half2_rn(z[4*q + 2], z[4*q + 3]);
            ((uint2*)p)[q] = u.v;
        }
    } else if constexpr (CH % 2 == 0) {
        #pragma unroll
        for (int q = 0; q < CH / 2; ++q)
            ((__half2*)p)[q] = __floats2half2_rn(z[2*q], z[2*q+1]);
    } else {
        #pragma unroll
        for (int o = 0; o < CH; ++o) p[o] = __float2half(z[o]);
    }
}

template<int CH>
__device__ __forceinline__ void accum_m_f16(float* acc, const __half* __restrict__ p) {
    if constexpr (CH % 8 == 0) {
        #pragma unroll
        for (int q = 0; q < CH / 8; ++q) {
            union { uint4 v; __half2 h2[4]; } u;
            u.v = ((const uint4*)p)[q];
            #pragma unroll
            for (int r = 0; r < 4; ++r) {
                float2 f = __half22float2(u.h2[r]);
                acc[q*8 + 2*r]     += f.x;
                acc[q*8 + 2*r + 1] += f.y;
            }
        }
    } else if constexpr (CH % 2 == 0) {
        #pragma unroll
        for (int q = 0; q < CH / 2; ++q) {
            float2 f = __half22float2(((const __half2*)p)[q]);
            acc[2*q] += f.x; acc[2*q+1] += f.y;
        }
    } else {
        #pragma unroll
        for (int o = 0; o < CH; ++o) acc[o] += __half2float(p[o]);
    }
}

__device__ __forceinline__ int cnt_unpack(unsigned v, int half) {
    return (int)((v >> (half * 16)) & 0xFFFFu);
}

// ===================================================================
// setup: (tile, octant, dst)-sorted slots; 16-bit packed counters
// slotmeta.pad carries local-dst (0..127); TS==128 means trash row
// ===================================================================

__global__ __launch_bounds__(256) void count8_k(const int* __restrict__ dst,
                                                const float* __restrict__ pseudo,
                                                unsigned* __restrict__ cnt4,
                                                unsigned short* __restrict__ rank16) {
    int e = blockIdx.x * 256 + threadIdx.x;
    if (e >= N_EDGES) return;
    int d = dst[e];
    size_t pb = (size_t)e * 3;
    int oct; float a, b, c;
    pseudo_to_of(pseudo[pb], pseudo[pb + 1], pseudo[pb + 2], oct, a, b, c);
    unsigned inc = 1u << ((oct & 1) * 16);
    unsigned r = atomicAdd(&cnt4[d * 4 + (oct >> 1)], inc);
    rank16[e] = (unsigned short)cnt_unpack(r, oct & 1);
}

__global__ __launch_bounds__(128) void scan_g1(const unsigned* __restrict__ cnt4,
                                               int* __restrict__ gsum) {
    __shared__ int red[128];
    int g = blockIdx.x, t = threadIdx.x;
    int tile = g >> 3, oct = g & 7;
    int n = tile * TS + t;
    red[t] = (n < N_NODES) ? cnt_unpack(cnt4[n * 4 + (oct >> 1)], oct & 1) : 0;
    __syncthreads();
    #pragma unroll
    for (int off = 64; off > 0; off >>= 1) {
        if (t < off) red[t] += red[t + off];
        __syncthreads();
    }
    if (t == 0) gsum[g] = red[0];
}

__global__ __launch_bounds__(1024) void scan_g2(const int* __restrict__ gsum,
                                                int* __restrict__ gbase,
                                                int* __restrict__ tot,
                                                unsigned char* __restrict__ winoct,
                                                uint4* __restrict__ slotmeta) {
    const int CHN = (NGRP + 1023) / 1024;   // 7
    __shared__ int ssum[1024];
    __shared__ int sraw;
    int t = threadIdx.x;
    int pv[CHN];
    int s = 0;
    #pragma unroll
    for (int j = 0; j < CHN; ++j) {
        int i = t * CHN + j;
        pv[j] = (i < NGRP) ? (((gsum[i] + 63) >> 6) << 6) : 0;
        s += pv[j];
    }
    ssum[t] = s;
    __syncthreads();
    #pragma unroll
    for (int off = 1; off < 1024; off <<= 1) {
        int u = (t >= off) ? ssum[t - off] : 0;
        __syncthreads();
        ssum[t] += u;
        __syncthreads();
    }
    int run = (t == 0) ? 0 : ssum[t - 1];
    #pragma unroll
    for (int j = 0; j < CHN; ++j) {
        int i = t * CHN + j;
        if (i < NGRP) { gbase[i] = run; run += pv[j]; }
    }
    if (t == 1023) sraw = ssum[1023];
    __syncthreads();
    int raw = sraw;                      // 64-multiple
    int totp = (raw + 255) & ~255;       // 256-multiple
    if (t == 0) { gbase[NGRP] = raw; tot[0] = raw; tot[1] = totp; }
    int fill = totp - raw;               // <= 192
    if (t < fill) {
        uint4 z; z.x = z.y = z.z = 0u; z.w = (unsigned)TS;   // trash ldst
        slotmeta[raw + t] = z;
    }
    if (t < (fill >> 6)) winoct[(raw >> 6) + t] = 0;
}

__global__ __launch_bounds__(128) void scan_g3(const unsigned* __restrict__ cnt4,
                                               const int* __restrict__ gbase,
                                               int* __restrict__ slotstart,
                                               unsigned char* __restrict__ winoct,
                                               uint4* __restrict__ slotmeta) {
    __shared__ int s[128];
    int g = blockIdx.x, t = threadIdx.x;
    int tile = g >> 3, oct = g & 7;
    int n = tile * TS + t;
    int c = (n < N_NODES) ? cnt_unpack(cnt4[n * 4 + (oct >> 1)], oct & 1) : 0;
    s[t] = c;
    __syncthreads();
    #pragma unroll
    for (int off = 1; off < 128; off <<= 1) {
        int u = (t >= off) ? s[t - off] : 0;
        __syncthreads();
        s[t] += u;
        __syncthreads();
    }
    int base = gbase[g];
    if (n < N_NODES) slotstart[n * 8 + oct] = base + s[t] - c;
    int cntg = s[127];
    int padded = ((cntg + 63) >> 6) << 6;
    for (int w = t; w < (padded >> 6); w += 128)
        winoct[(base >> 6) + w] = (unsigned char)oct;
    for (int i = t; i < padded - cntg; i += 128) {
        uint4 z; z.x = z.y = z.z = 0u; z.w = (unsigned)TS;   // trash ldst
        slotmeta[base + cntg + i] = z;
    }
}

__global__ __launch_bounds__(256) void scatter2_k(const int* __restrict__ src,
                                                  const int* __restrict__ dst,
                                                  const float* __restrict__ pseudo,
                                                  const unsigned short* __restrict__ rank16,
                                                  const int* __restrict__ slotstart,
                                                  uint4* __restrict__ slotmeta) {
    int e = blockIdx.x * 256 + threadIdx.x;
    if (e >= N_EDGES) return;
    int d = dst[e];
    size_t pb = (size_t)e * 3;
    int oct; float fr0, fr1, fr2;
    pseudo_to_of(pseudo[pb], pseudo[pb + 1], pseudo[pb + 2], oct, fr0, fr1, fr2);
    int slot = slotstart[d * 8 + oct] + (int)rank16[e];
    union { uint4 v; struct { int s; __half2 f01; __half2 f2x; unsigned pad; } t; } su;
    su.t.s   = src[e];
    su.t.f01 = __floats2half2_rn(fr0, fr1);
    su.t.f2x = __floats2half2_rn(fr2, 0.0f);
    su.t.pad = (unsigned)(d & (TS - 1));     // local dst row
    slotmeta[slot] = su.v;
}

// ===================================================================
// W prep: fragment-ordered fp16 B tables, all 4 MFMA layers in one launch
// ===================================================================

template<int Fin, int Fout>
__device__ __forceinline__ void wprep_elem(const float* __restrict__ W,
                                           _Float16* __restrict__ WB, int i) {
    constexpr int KT = (8 * Fin) / 32;
    constexpr int NT = (Fout + 15) / 16;
    int j    = i & 7;
    int lane = (i >> 3) & 63;
    int rest = i >> 9;
    int nt = rest % NT; rest /= NT;
    int kt = rest % KT;
    int g  = rest / KT;
    int kb = lane >> 4, n = lane & 15;
    int k  = kt * 32 + kb * 8 + j;
    int b  = k / Fin, f = k % Fin;
    int bidx = (g & 1) + 3 * ((g >> 1) & 1) + 9 * ((g >> 2) & 1);
    int idx  = bidx + (b & 1) + 3 * ((b >> 1) & 1) + 9 * ((b >> 2) & 1);
    int col  = nt * 16 + n;
    float v = (col < Fout) ? W[((size_t)idx * Fin + f) * Fout + col] : 0.0f;
    WB[i] = (_Float16)v;
}

#define WS2 8192
#define WS3 32768
#define WS4 32768
#define WS5 16384

__global__ __launch_bounds__(256) void wprep_all_k(const float* __restrict__ W2,
                                                   const float* __restrict__ W3,
                                                   const float* __restrict__ W4,
                                                   const float* __restrict__ W5,
                                                   _Float16* __restrict__ WB2,
                                                   _Float16* __restrict__ WB3,
                                                   _Float16* __restrict__ WB4,
                                                   _Float16* __restrict__ WB5) {
    int i = blockIdx.x * 256 + threadIdx.x;
    if (i < WS2) { wprep_elem<8, 16>(W2, WB2, i); return; }
    i -= WS2;
    if (i < WS3) { wprep_elem<16, 32>(W3, WB3, i); return; }
    i -= WS3;
    if (i < WS4) { wprep_elem<32, 16>(W4, WB4, i); return; }
    i -= WS4;
    if (i < WS5) { wprep_elem<16, 8>(W5, WB5, i); return; }
}

// ===================================================================
// FUSED MFMA layer kernel: one block per 128-node dst tile.
// Windows of the tile's contiguous slot range -> MFMA messages ->
// ds_add_f32 into LDS accumulator -> root+bias+ELU epilogue.
// ===================================================================

template<int Fin, int Fout>
__global__ __launch_bounds__(256) void fused_mfma_k(const __half* __restrict__ h,
                                                    const uint4* __restrict__ slotmeta,
                                                    const unsigned char* __restrict__ winoct,
                                                    const int* __restrict__ gbase,
                                                    const _Float16* __restrict__ WB,
                                                    const float* __restrict__ root,
                                                    const float* __restrict__ bias,
                                                    __half* __restrict__ hout) {
    constexpr int KT = (8 * Fin) / 32;
    constexpr int NT = (Fout + 15) / 16;
    constexpr int LOG2FIN = (Fin == 8) ? 3 : (Fin == 16) ? 4 : 5;
    constexpr int AS = Fout + 1;          // odd stride -> bank spread
    constexpr int REM = Fout & 15;        // partial last n-tile (Fout=8)

    __shared__ float accs[(TS + 1) * AS];   // row TS = trash
    __shared__ unsigned short sld[4][64];

    const int tile = blockIdx.x;
    const int tid = threadIdx.x, wv = tid >> 6, lane = tid & 63;

    for (int i = tid; i < (TS + 1) * AS; i += 256) accs[i] = 0.0f;
    __syncthreads();

    const int s0 = gbase[tile * 8];
    const int s1 = gbase[tile * 8 + 8];
    const int kb = lane >> 4;
    const f16x8* __restrict__ WBv = (const f16x8*)WB;
    const f16x8* __restrict__ hv  = (const f16x8*)h;

    for (int wbase = s0 + wv * 64; wbase < s1; wbase += 256) {
        int oct = winoct[wbase >> 6];
        oct = __builtin_amdgcn_readfirstlane(oct);

        int   sE[4];
        float g0[4], h0[4], g1[4], h1[4], g2[4], h2v[4];
        #pragma unroll
        for (int mt = 0; mt < 4; ++mt) {
            union { uint4 v; struct { int s; __half2 f01; __half2 f2x; unsigned pad; } t; } u;
            u.v = slotmeta[wbase + mt * 16 + (lane & 15)];
            sE[mt] = u.t.s;
            if (lane < 16) sld[wv][mt * 16 + lane] = (unsigned short)u.t.pad;
            float2 f01 = __half22float2(u.t.f01);
            float2 f2x = __half22float2(u.t.f2x);
            g0[mt] = 1.0f - f01.x; h0[mt] = f01.x;
            g1[mt] = 1.0f - f01.y; h1[mt] = f01.y;
            g2[mt] = 1.0f - f2x.x; h2v[mt] = f2x.x;
        }

        f32x4 accr[4][NT];
        #pragma unroll
        for (int mt = 0; mt < 4; ++mt)
            #pragma unroll
            for (int nt = 0; nt < NT; ++nt)
                accr[mt][nt] = (f32x4){0.0f, 0.0f, 0.0f, 0.0f};

        #pragma unroll
        for (int kt = 0; kt < KT; ++kt) {
            f16x8 bf[NT];
            #pragma unroll
            for (int nt = 0; nt < NT; ++nt)
                bf[nt] = WBv[((oct * KT + kt) * NT + nt) * 64 + lane];

            const int k0 = kt * 32 + kb * 8;
            const int b  = k0 >> LOG2FIN;
            const int f8 = (k0 & (Fin - 1)) >> 3;

            #pragma unroll
            for (int mt = 0; mt < 4; ++mt) {
                f16x8 xa = hv[(size_t)sE[mt] * (Fin / 8) + f8];
                float w = ((b & 1) ? h0[mt] : g0[mt])
                        * ((b & 2) ? h1[mt] : g1[mt])
                        * ((b & 4) ? h2v[mt] : g2[mt]);
                _Float16 wh = (_Float16)w;
                f16x8 av;
                #pragma unroll
                for (int j = 0; j < 8; ++j) av[j] = xa[j] * wh;
                #pragma unroll
                for (int nt = 0; nt < NT; ++nt)
                    accr[mt][nt] = __builtin_amdgcn_mfma_f32_16x16x32_f16(av, bf[nt], accr[mt][nt], 0, 0, 0);
            }
        }

        // D fragment (e = mt*16 + (lane>>4)*4 + q, o = nt*16 + (lane&15)) -> LDS add
        #pragma unroll
        for (int mt = 0; mt < 4; ++mt) {
            #pragma unroll
            for (int q = 0; q < 4; ++q) {
                int e = mt * 16 + (lane >> 4) * 4 + q;
                int r = (int)sld[wv][e];
                float* ap = &accs[r * AS + (lane & 15)];
                #pragma unroll
                for (int nt = 0; nt < NT; ++nt) {
                    bool ok = (REM == 0) || (nt < NT - 1) || ((lane & 15) < REM);
                    if (ok) atomicAdd(&ap[nt * 16], accr[mt][nt][q]);
                }
            }
        }
    }
    __syncthreads();

    // epilogue: root + bias + ELU, coalesced fp16 store
    if (tid < TS) {
        int n = tile * TS + tid;
        if (n < N_NODES) {
            float xr[Fin];
            loadanyT<Fin>(h + (size_t)n * Fin, xr);
            float z[Fout];
            #pragma unroll
            for (int o = 0; o < Fout; ++o) z[o] = bias[o] + accs[tid * AS + o];
            #pragma unroll
            for (int f = 0; f < Fin; ++f) {
                #pragma unroll
                for (int o = 0; o < Fout; ++o)
                    z[o] = fmaf(xr[f], root[f * Fout + o], z[o]);
            }
            float zz[Fout];
            #pragma unroll
            for (int o = 0; o < Fout; ++o) {
                float t = z[o];
                zz[o] = t > 0.0f ? t : expm1f(t);
            }
            storeanyT<Fout>(hout + (size_t)n * Fout, zz);
        }
    }
}

// ===================================================================
// VALU msg kernel (L1/L6 + fallback tiers)
// ===================================================================

template<int Fin, int Fout, int CH, typename TIn>
__global__ __launch_bounds__(256) void msg_k(const TIn* __restrict__ h,
                                             const uint4* __restrict__ slotmeta,
                                             const unsigned char* __restrict__ winoct,
                                             const int* __restrict__ tot,
                                             const float* __restrict__ W,
                                             __half* __restrict__ m,
                                             int coff) {
    int base = blockIdx.x * 256;
    if (base >= tot[1]) return;
    int wv = threadIdx.x >> 6;
    int g = winoct[(base >> 6) + wv];
    g = __builtin_amdgcn_readfirstlane(g);
    const int bidx = (g & 1) + 3 * ((g >> 1) & 1) + 9 * ((g >> 2) & 1);

    int j = base + threadIdx.x;

    union { uint4 v; struct { int s; __half2 f01; __half2 f2x; unsigned pad; } t; } u;
    u.v = slotmeta[j];
    int s = u.t.s;
    float2 f01 = __half22float2(u.t.f01);
    float2 f2x = __half22float2(u.t.f2x);
    float fr0 = f01.x, fr1 = f01.y, fr2 = f2x.x;
    float a0[2] = {1.0f - fr0, fr0};
    float a1[2] = {1.0f - fr1, fr1};
    float a2[2] = {1.0f - fr2, fr2};
    float w[8];
    #pragma unroll
    for (int b = 0; b < 8; ++b)
        w[b] = a0[b & 1] * a1[(b >> 1) & 1] * a2[(b >> 2) & 1];

    float x[Fin];
    loadanyT<Fin>(h + (size_t)s * Fin, x);

    float z[CH];
    #pragma unroll
    for (int o = 0; o < CH; ++o) z[o] = 0.0f;

    #pragma unroll
    for (int b = 0; b < 8; ++b) {
        const int idx = bidx + (b & 1) + 3 * ((b >> 1) & 1) + 9 * ((b >> 2) & 1);
        const float* __restrict__ wp = W + (size_t)idx * (Fin * Fout) + coff;
        float wb = w[b];
        #pragma unroll
        for (int f = 0; f < Fin; ++f) {
            float a = wb * x[f];
            #pragma unroll
            for (int o = 0; o < CH; ++o) z[o] = fmaf(a, wp[f * Fout + o], z[o]);
        }
    }

    storeanyT<CH>(m + (size_t)j * CH, z);
}

// ===================================================================
// gather kernel (round-9 proven version): 8 contiguous runs per node
// ===================================================================

template<int Fin, int Fout, int CH, typename TIn, typename TOut>
__global__ __launch_bounds__(256) void gather_k(const TIn* __restrict__ hin,
                                                const __half* __restrict__ m,
                                                const int* __restrict__ slotstart,
                                                const unsigned* __restrict__ cnt4,
                                                const float* __restrict__ root,
                                                const float* __restrict__ bias,
                                                TOut* __restrict__ hout,
                                                int coff) {
    int n = blockIdx.x * 256 + threadIdx.x;
    if (n >= N_NODES) return;

    float acc[CH];
    #pragma unroll
    for (int o = 0; o < CH; ++o) acc[o] = bias[coff + o];

    float x[Fin];
    loadanyT<Fin>(hin + (size_t)n * Fin, x);
    #pragma unroll
    for (int f = 0; f < Fin; ++f) {
        #pragma unroll
        for (int o = 0; o < CH; ++o)
            acc[o] = fmaf(x[f], root[f * Fout + coff + o], acc[o]);
    }

    int4 sa = ((const int4*)slotstart)[n * 2];
    int4 sb = ((const int4*)slotstart)[n * 2 + 1];
    uint4 cp = ((const uint4*)cnt4)[n];
    int ss[8] = {sa.x, sa.y, sa.z, sa.w, sb.x, sb.y, sb.z, sb.w};
    int cc[8];
    cc[0] = (int)(cp.x & 0xFFFFu); cc[1] = (int)(cp.x >> 16);
    cc[2] = (int)(cp.y & 0xFFFFu); cc[3] = (int)(cp.y >> 16);
    cc[4] = (int)(cp.z & 0xFFFFu); cc[5] = (int)(cp.z >> 16);
    cc[6] = (int)(cp.w & 0xFFFFu); cc[7] = (int)(cp.w >> 16);

    #pragma unroll
    for (int oct = 0; oct < 8; ++oct) {
        int p = ss[oct];
        for (int j = 0; j < cc[oct]; ++j)
            accum_m_f16<CH>(acc, m + (size_t)(p + j) * CH);
    }

    float zz[CH];
    #pragma unroll
    for (int o = 0; o < CH; ++o) {
        float t = acc[o];
        zz[o] = t > 0.0f ? t : expm1f(t);
    }
    storeanyT<CH>(hout + (size_t)n * Fout + coff, zz);
}

// ===================================================================
// FALLBACK PATH (atomic, fp32) — only if workspace is tiny
// ===================================================================

template<int Fin, int Fout>
__global__ __launch_bounds__(256) void init_out_k(const float* __restrict__ h,
                                                  const float* __restrict__ root,
                                                  const float* __restrict__ bias,
                                                  float* __restrict__ out) {
    int n = blockIdx.x * 256 + threadIdx.x;
    if (n >= N_NODES) return;
    float xr[Fin];
    #pragma unroll
    for (int f = 0; f < Fin; ++f) xr[f] = h[(size_t)n * Fin + f];
    float z[Fout];
    #pragma unroll
    for (int o = 0; o < Fout; ++o) z[o] = bias[o];
    #pragma unroll
    for (int f = 0; f < Fin; ++f)
        #pragma unroll
        for (int o = 0; o < Fout; ++o) z[o] += xr[f] * root[f * Fout + o];
    #pragma unroll
    for (int o = 0; o < Fout; ++o) out[(size_t)n * Fout + o] = z[o];
}

template<int Fin, int Fout>
__global__ __launch_bounds__(256) void edge_k(const float* __restrict__ h,
                                              const int* __restrict__ src,
                                              const int* __restrict__ dst,
                                              const float* __restrict__ pseudo,
                                              const float* __restrict__ W,
                                              float* __restrict__ out) {
    constexpr int KFF = Fin * Fout;
    constexpr int STRIDE = KFF + 1;
    __shared__ float sW[27 * STRIDE];
    for (int i = threadIdx.x; i < 27 * KFF; i += 256) {
        int k = i / KFF;
        sW[k * STRIDE + (i - k * KFF)] = W[i];
    }
    __syncthreads();
    int e = blockIdx.x * 256 + threadIdx.x;
    if (e >= N_EDGES) return;
    int s = src[e], d = dst[e];
    size_t pb = (size_t)e * 3;
    int oct; float fr0, fr1, fr2;
    pseudo_to_of(pseudo[pb], pseudo[pb+1], pseudo[pb+2], oct, fr0, fr1, fr2);
    int i0 = oct & 1, i1 = (oct >> 1) & 1, i2 = (oct >> 2) & 1;
    float a0[2] = {1.0f - fr0, fr0};
    float a1[2] = {1.0f - fr1, fr1};
    float a2[2] = {1.0f - fr2, fr2};
    float xr[Fin];
    #pragma unroll
    for (int f = 0; f < Fin; ++f) xr[f] = h[(size_t)s * Fin + f];
    float z[Fout];
    #pragma unroll
    for (int o = 0; o < Fout; ++o) z[o] = 0.0f;
    #pragma unroll
    for (int b = 0; b < 8; ++b) {
        int idx = (i0 + (b & 1)) + 3 * (i1 + ((b >> 1) & 1)) + 9 * (i2 + ((b >> 2) & 1));
        float wb = a0[b & 1] * a1[(b >> 1) & 1] * a2[(b >> 2) & 1];
        const float* wp = &sW[idx * STRIDE];
        #pragma unroll
        for (int f = 0; f < Fin; ++f) {
            float a = wb * xr[f];
            #pragma unroll
            for (int o = 0; o < Fout; ++o) z[o] += a * wp[f * Fout + o];
        }
    }
    float* op = out + (size_t)d * Fout;
    #pragma unroll
    for (int o = 0; o < Fout; ++o) atomicAdd(&op[o], z[o]);
}

__global__ __launch_bounds__(256) void elu_k(float* __restrict__ p, int total) {
    int i = blockIdx.x * 256 + threadIdx.x;
    if (i < total) {
        float t = p[i];
        p[i] = t > 0.0f ? t : expm1f(t);
    }
}

// ===================================================================
// host
// ===================================================================

template<int Fin, int Fout, typename TIn, typename TOut>
static void run_layer_valu(const TIn* hin, TOut* hout,
                           const float* W, const float* root, const float* bias,
                           const uint4* slotmeta, const unsigned char* winoct,
                           const int* tot, const int* slotstart, const unsigned* cnt4,
                           __half* m, int chunk, hipStream_t stream) {
    const int GN = (N_NODES + 255) / 256;
    if (Fout <= chunk) {
        msg_k<Fin, Fout, Fout, TIn><<<GRID_E2, 256, 0, stream>>>(hin, slotmeta, winoct, tot, W, m, 0);
        gather_k<Fin, Fout, Fout, TIn, TOut><<<GN, 256, 0, stream>>>(hin, m, slotstart, cnt4, root, bias, hout, 0);
        return;
    }
    if constexpr (Fout > 16) {
        if (chunk == 16) {
            for (int p = 0; p < Fout / 16; ++p) {
                msg_k<Fin, Fout, 16, TIn><<<GRID_E2, 256, 0, stream>>>(hin, slotmeta, winoct, tot, W, m, 16 * p);
                gather_k<Fin, Fout, 16, TIn, TOut><<<GN, 256, 0, stream>>>(hin, m, slotstart, cnt4, root, bias, hout, 16 * p);
            }
            return;
        }
    }
    if constexpr (Fout > 8) {
        if (chunk == 8) {
            for (int p = 0; p < Fout / 8; ++p) {
                msg_k<Fin, Fout, 8, TIn><<<GRID_E2, 256, 0, stream>>>(hin, slotmeta, winoct, tot, W, m, 8 * p);
                gather_k<Fin, Fout, 8, TIn, TOut><<<GN, 256, 0, stream>>>(hin, m, slotstart, cnt4, root, bias, hout, 8 * p);
            }
            return;
        }
    }
    if constexpr (Fout > 4) {
        if (chunk == 4) {
            for (int p = 0; p < Fout / 4; ++p) {
                msg_k<Fin, Fout, 4, TIn><<<GRID_E2, 256, 0, stream>>>(hin, slotmeta, winoct, tot, W, m, 4 * p);
                gather_k<Fin, Fout, 4, TIn, TOut><<<GN, 256, 0, stream>>>(hin, m, slotstart, cnt4, root, bias, hout, 4 * p);
            }
            return;
        }
    }
    if constexpr (Fout > 2) {
        if (chunk == 2) {
            for (int p = 0; p < Fout / 2; ++p) {
                msg_k<Fin, Fout, 2, TIn><<<GRID_E2, 256, 0, stream>>>(hin, slotmeta, winoct, tot, W, m, 2 * p);
                gather_k<Fin, Fout, 2, TIn, TOut><<<GN, 256, 0, stream>>>(hin, m, slotstart, cnt4, root, bias, hout, 2 * p);
            }
            return;
        }
    }
}

template<int Fin, int Fout>
static void run_layer_old(const float* hin, float* hout,
                          const float* W, const float* root, const float* bias,
                          const int* src, const int* dst, const float* pseudo,
                          hipStream_t stream) {
    init_out_k<Fin, Fout><<<(N_NODES + 255) / 256, 256, 0, stream>>>(hin, root, bias, hout);
    edge_k<Fin, Fout><<<(N_EDGES + 255) / 256, 256, 0, stream>>>(hin, src, dst, pseudo, W, hout);
    int total = N_NODES * Fout;
    elu_k<<<(total + 255) / 256, 256, 0, stream>>>(hout, total);
}

extern "C" void kernel_launch(void* const* d_in, const int* in_sizes, int n_in,
                              void* d_out, int out_size, void* d_ws, size_t ws_size,
                              hipStream_t stream) {
    const float* x      = (const float*)d_in[0];
    const int*   ei     = (const int*)d_in[1];
    const float* pseudo = (const float*)d_in[2];
    const int* src = ei;
    const int* dst = ei + N_EDGES;

    const float* W[6]; const float* R[6]; const float* B[6];
    for (int i = 0; i < 6; ++i) {
        W[i] = (const float*)d_in[3 + 3 * i];
        R[i] = (const float*)d_in[4 + 3 * i];
        B[i] = (const float*)d_in[5 + 3 * i];
    }
    float* out = (float*)d_out;
    char* ws = (char*)d_ws;

    // ---- workspace plan: tier 0 = fused (m @ CH=8); tiers 8/4/2 = valu ----
    const int tiers[3] = {8, 4, 2};
    int chunk = 0;            // m chunk for the VALU layers
    int fused = 0;
    size_t o_hA = 0, o_hB = 0, o_c4 = 0, o_ss = 0, o_rk = 0, o_meta = 0,
           o_wo = 0, o_sm = 0, o_wb = 0, o_m = 0;
    for (int t = 0; t < 3; ++t) {
        int c = tiers[t];
        size_t off = 0;
        auto alloc = [&](size_t bytes) { size_t cur = off; off = (off + bytes + 255) & ~(size_t)255; return cur; };
        size_t a_hA   = alloc((size_t)N_NODES * 32 * 2);        // fp16 activations
        size_t a_hB   = alloc((size_t)N_NODES * 32 * 2);
        size_t a_c4   = alloc((size_t)N_NODES * 4 * 4);         // packed 16-bit counters
        size_t a_ss   = alloc((size_t)N_NODES * 8 * 4);
        size_t a_rk   = alloc((size_t)N_EDGES * 2);
        size_t a_meta = alloc((size_t)(2 * NGRP + 16) * 4);     // gsum, gbase(+1), tot
        size_t a_wo   = alloc((size_t)(E_PAD2 / 64));
        size_t a_sm   = alloc((size_t)E_PAD2 * 16);
        size_t a_wb   = alloc((size_t)4 * 65536 * 2);
        size_t a_m    = alloc((size_t)E_PAD2 * c * 2);
        if (off <= ws_size) {
            chunk = c; fused = (t == 0);
            o_hA = a_hA; o_hB = a_hB; o_c4 = a_c4; o_ss = a_ss; o_rk = a_rk;
            o_meta = a_meta; o_wo = a_wo; o_sm = a_sm; o_wb = a_wb; o_m = a_m;
            break;
        }
    }

    if (chunk > 0) {
        __half* hA     = (__half*)(ws + o_hA);
        __half* hB     = (__half*)(ws + o_hB);
        unsigned* cnt4 = (unsigned*)(ws + o_c4);
        int*   slotst  = (int*)(ws + o_ss);
        unsigned short* rank16 = (unsigned short*)(ws + o_rk);
        int*   gsum    = (int*)(ws + o_meta);
        int*   gbase   = gsum + NGRP;                 // NGRP+1 entries
        int*   tot     = gbase + NGRP + 1;
        unsigned char* winoct = (unsigned char*)(ws + o_wo);
        uint4* slotmeta= (uint4*)(ws + o_sm);
        _Float16* WB2  = (_Float16*)(ws + o_wb);
        _Float16* WB3  = WB2 + 65536;
        _Float16* WB4  = WB2 + 2 * 65536;
        _Float16* WB5  = WB2 + 3 * 65536;
        __half* m      = (__half*)(ws + o_m);

        hipMemsetAsync(cnt4, 0, (size_t)N_NODES * 4 * 4, stream);

        count8_k<<<N_EDGES / 256, 256, 0, stream>>>(dst, pseudo, cnt4, rank16);
        scan_g1<<<NGRP, 128, 0, stream>>>(cnt4, gsum);
        scan_g2<<<1, 1024, 0, stream>>>(gsum, gbase, tot, winoct, slotmeta);
        scan_g3<<<NGRP, 128, 0, stream>>>(cnt4, gbase, slotst, winoct, slotmeta);
        scatter2_k<<<N_EDGES / 256, 256, 0, stream>>>(src, dst, pseudo, rank16, slotst, slotmeta);

        if (fused) {
            wprep_all_k<<<(WS2 + WS3 + WS4 + WS5 + 255) / 256, 256, 0, stream>>>(
                W[1], W[2], W[3], W[4], WB2, WB3, WB4, WB5);

            // L1 (VALU msg+gather, fp32 in -> fp16 out)
            run_layer_valu<1, 8, float, __half>(x, hA, W[0], R[0], B[0], slotmeta, winoct, tot,
                                                slotst, cnt4, m, chunk, stream);
            // L2-L5: fused MFMA per-tile kernels (no m round-trip)
            fused_mfma_k<8, 16><<<NTILE, 256, 0, stream>>>(hA, slotmeta, winoct, gbase, WB2, R[1], B[1], hB);
            fused_mfma_k<16, 32><<<NTILE, 256, 0, stream>>>(hB, slotmeta, winoct, gbase, WB3, R[2], B[2], hA);
            fused_mfma_k<32, 16><<<NTILE, 256, 0, stream>>>(hA, slotmeta, winoct, gbase, WB4, R[3], B[3], hB);
            fused_mfma_k<16, 8><<<NTILE, 256, 0, stream>>>(hB, slotmeta, winoct, gbase, WB5, R[4], B[4], hA);
            // L6 (VALU msg+gather, fp16 in -> fp32 out)
            run_layer_valu<8, 1, __half, float>(hA, out, W[5], R[5], B[5], slotmeta, winoct, tot,
                                                slotst, cnt4, m, chunk, stream);
        } else {
            run_layer_valu<1, 8, float, __half>(x, hA, W[0], R[0], B[0], slotmeta, winoct, tot,
                                                slotst, cnt4, m, chunk, stream);
            run_layer_valu<8, 16, __half, __half>(hA, hB, W[1], R[1], B[1], slotmeta, winoct, tot,
                                                  slotst, cnt4, m, chunk, stream);
            run_layer_valu<16, 32, __half, __half>(hB, hA, W[2], R[2], B[2], slotmeta, winoct, tot,
                                                   slotst, cnt4, m, chunk, stream);
            run_layer_valu<32, 16, __half, __half>(hA, hB, W[3], R[3], B[3], slotmeta, winoct, tot,
                                                   slotst, cnt4, m, chunk, stream);
            run_layer_valu<16, 8, __half, __half>(hB, hA, W[4], R[4], B[4], slotmeta, winoct, tot,
                                                  slotst, cnt4, m, chunk, stream);
            run_layer_valu<8, 1, __half, float>(hA, out, W[5], R[5], B[5], slotmeta, winoct, tot,
                                                slotst, cnt4, m, chunk, stream);
        }
    } else {
        float* hAf = (float*)ws;
        float* hBf = hAf + (size_t)N_NODES * 32;
        run_layer_old<1, 8>  (x,   hAf, W[0], R[0], B[0], src, dst, pseudo, stream);
        run_layer_old<8, 16> (hAf, hBf, W[1], R[1], B[1], src, dst, pseudo, stream);
        run_layer_old<16, 32>(hBf, hAf, W[2], R[2], B[2], src, dst, pseudo, stream);
        run_layer_old<32, 16>(hAf, hBf, W[3], R[3], B[3], src, dst, pseudo, stream);
        run_layer_old<16, 8> (hBf, hAf, W[4], R[4], B[4], src, dst, pseudo, stream);
        run_layer_old<8, 1>  (hAf, out, W[5], R[5], B[5], src, dst, pseudo, stream);
    }
}

// Round 13
// 409.545 us; speedup vs baseline: 2.7323x; 2.7323x over previous
//
#include <hip/hip_runtime.h>
#include <hip/hip_fp16.h>

#define N_NODES 100000
#define N_EDGES 1600000
#define TS      1024
#define NTILE   ((N_NODES + TS - 1) / TS)            // 98
#define NGRP    (NTILE * 8)                          // 784 (tile, octant) groups
#define E_PAD2  (N_EDGES + NGRP * 64 + 256)          // padded slot capacity
#define GRID_E2 (E_PAD2 / 256)

typedef _Float16 f16x8 __attribute__((ext_vector_type(8)));
typedef float    f32x4 __attribute__((ext_vector_type(4)));

// ===================================================================
// helpers
// ===================================================================

__device__ __forceinline__ void pseudo_to_of(float p0, float p1, float p2,
                                             int& oct, float& fr0, float& fr1, float& fr2) {
    float v0 = p0 * 2.0f, v1 = p1 * 2.0f, v2 = p2 * 2.0f;
    int i0 = v0 >= 1.0f, i1 = v1 >= 1.0f, i2 = v2 >= 1.0f;
    fr0 = v0 - (float)i0; fr1 = v1 - (float)i1; fr2 = v2 - (float)i2;
    oct = i0 + 2 * i1 + 4 * i2;
}

template<int Fin>
__device__ __forceinline__ void loadanyT(const float* __restrict__ hp, float* x) {
    if constexpr (Fin % 4 == 0) {
        const float4* xv = reinterpret_cast<const float4*>(hp);
        #pragma unroll
        for (int f = 0; f < Fin / 4; ++f) {
            float4 t = xv[f];
            x[4*f+0] = t.x; x[4*f+1] = t.y; x[4*f+2] = t.z; x[4*f+3] = t.w;
        }
    } else {
        #pragma unroll
        for (int f = 0; f < Fin; ++f) x[f] = hp[f];
    }
}

template<int Fin>
__device__ __forceinline__ void loadanyT(const __half* __restrict__ hp, float* x) {
    if constexpr (Fin % 8 == 0) {
        #pragma unroll
        for (int r = 0; r < Fin / 8; ++r) {
            union { uint4 v; __half2 h2[4]; } u;
            u.v = ((const uint4*)hp)[r];
            #pragma unroll
            for (int q = 0; q < 4; ++q) {
                float2 f = __half22float2(u.h2[q]);
                x[r*8 + 2*q]     = f.x;
                x[r*8 + 2*q + 1] = f.y;
            }
        }
    } else {
        #pragma unroll
        for (int f = 0; f < Fin; ++f) x[f] = __half2float(hp[f]);
    }
}

template<int CH>
__device__ __forceinline__ void storeanyT(float* __restrict__ p, const float* z) {
    if constexpr (CH % 4 == 0) {
        #pragma unroll
        for (int o = 0; o < CH / 4; ++o) {
            float4 t; t.x = z[4*o]; t.y = z[4*o+1]; t.z = z[4*o+2]; t.w = z[4*o+3];
            ((float4*)p)[o] = t;
        }
    } else if constexpr (CH % 2 == 0) {
        #pragma unroll
        for (int o = 0; o < CH / 2; ++o) {
            float2 t; t.x = z[2*o]; t.y = z[2*o+1];
            ((float2*)p)[o] = t;
        }
    } else {
        #pragma unroll
        for (int o = 0; o < CH; ++o) p[o] = z[o];
    }
}

template<int CH>
__device__ __forceinline__ void storeanyT(__half* __restrict__ p, const float* z) {
    if constexpr (CH % 8 == 0) {
        #pragma unroll
        for (int q = 0; q < CH / 8; ++q) {
            union { uint4 v; __half2 h2[4]; } u;
            #pragma unroll
            for (int r = 0; r < 4; ++r)
                u.h2[r] = __floats2half2_rn(z[q*8 + 2*r], z[q*8 + 2*r + 1]);
            ((uint4*)p)[q] = u.v;
        }
    } else if constexpr (CH % 4 == 0) {
        #pragma unroll
        for (int q = 0; q < CH / 4; ++q) {
            union { uint2 v; __half2 h2[2]; } u;
            u.h2[0] = __floats2half2_rn(z[4*q],     z[4*q + 1]);
            u.h2[1] = __floats2half2_rn(z[4*q + 2], z[4*q + 3]);
            ((uint2*)p)[q] = u.v;
        }
    } else if constexpr (CH % 2 == 0) {
        #pragma unroll
        for (int q = 0; q < CH / 2; ++q)
            ((__half2*)p)[q] = __floats2half2_rn(z[2*q], z[2*q+1]);
    } else {
        #pragma unroll
        for (int o = 0; o < CH; ++o) p[o] = __float2half(z[o]);
    }
}

template<int CH>
__device__ __forceinline__ void accum_m_f16(float* acc, const __half* __restrict__ p) {
    if constexpr (CH % 8 == 0) {
        #pragma unroll
        for (int q = 0; q < CH / 8; ++q) {
            union { uint4 v; __half2 h2[4]; } u;
            u.v = ((const uint4*)p)[q];
            #pragma unroll
            for (int r = 0; r < 4; ++r) {
                float2 f = __half22float2(u.h2[r]);
                acc[q*8 + 2*r]     += f.x;
                acc[q*8 + 2*r + 1] += f.y;
            }
        }
    } else if constexpr (CH % 2 == 0) {
        #pragma unroll
        for (int q = 0; q < CH / 2; ++q) {
            float2 f = __half22float2(((const __half2*)p)[q]);
            acc[2*q] += f.x; acc[2*q+1] += f.y;
        }
    } else {
        #pragma unroll
        for (int o = 0; o < CH; ++o) acc[o] += __half2float(p[o]);
    }
}

__device__ __forceinline__ int cnt_unpack(unsigned v, int half) {
    return (int)((v >> (half * 16)) & 0xFFFFu);
}

// ===================================================================
// setup: (tile, octant, dst)-sorted slots; 16-bit packed counters
// ===================================================================

__global__ __launch_bounds__(256) void count8_k(const int* __restrict__ dst,
                                                const float* __restrict__ pseudo,
                                                unsigned* __restrict__ cnt4,
                                                unsigned short* __restrict__ rank16) {
    int e = blockIdx.x * 256 + threadIdx.x;
    if (e >= N_EDGES) return;
    int d = dst[e];
    size_t pb = (size_t)e * 3;
    int oct; float a, b, c;
    pseudo_to_of(pseudo[pb], pseudo[pb + 1], pseudo[pb + 2], oct, a, b, c);
    unsigned inc = 1u << ((oct & 1) * 16);
    unsigned r = atomicAdd(&cnt4[d * 4 + (oct >> 1)], inc);
    rank16[e] = (unsigned short)cnt_unpack(r, oct & 1);
}

__global__ __launch_bounds__(256) void scan_g1(const unsigned* __restrict__ cnt4,
                                               int* __restrict__ gsum) {
    __shared__ int red[256];
    int g = blockIdx.x, t = threadIdx.x;
    int tile = g >> 3, oct = g & 7;
    int s = 0;
    #pragma unroll
    for (int q = 0; q < 4; ++q) {
        int n = tile * TS + t * 4 + q;
        if (n < N_NODES) s += cnt_unpack(cnt4[n * 4 + (oct >> 1)], oct & 1);
    }
    red[t] = s;
    __syncthreads();
    #pragma unroll
    for (int off = 128; off > 0; off >>= 1) {
        if (t < off) red[t] += red[t + off];
        __syncthreads();
    }
    if (t == 0) gsum[g] = red[0];
}

__global__ __launch_bounds__(1024) void scan_g2(const int* __restrict__ gsum,
                                                int* __restrict__ gbase,
                                                int* __restrict__ tot,
                                                unsigned char* __restrict__ winoct,
                                                uint4* __restrict__ slotmeta) {
    __shared__ int s[1024];
    __shared__ int sraw;
    int t = threadIdx.x;
    int v = 0;
    if (t < NGRP) v = ((gsum[t] + 63) >> 6) << 6;
    s[t] = v;
    __syncthreads();
    #pragma unroll
    for (int off = 1; off < 1024; off <<= 1) {
        int u = (t >= off) ? s[t - off] : 0;
        __syncthreads();
        s[t] += u;
        __syncthreads();
    }
    if (t < NGRP) gbase[t] = s[t] - v;
    if (t == NGRP - 1) sraw = s[t];
    __syncthreads();
    int raw = sraw;
    int totp = (raw + 255) & ~255;
    if (t == 0) { tot[0] = raw; tot[1] = totp; }
    int fill = totp - raw;
    if (t < fill) {
        uint4 z; z.x = z.y = z.z = z.w = 0u;
        slotmeta[raw + t] = z;
    }
    if (t < (fill >> 6)) winoct[(raw >> 6) + t] = 0;
}

__global__ __launch_bounds__(256) void scan_g3(const unsigned* __restrict__ cnt4,
                                               const int* __restrict__ gbase,
                                               int* __restrict__ slotstart,
                                               unsigned char* __restrict__ winoct,
                                               uint4* __restrict__ slotmeta) {
    __shared__ int s[256];
    int g = blockIdx.x, t = threadIdx.x;
    int tile = g >> 3, oct = g & 7;
    int c[4];
    int sum = 0;
    #pragma unroll
    for (int q = 0; q < 4; ++q) {
        int n = tile * TS + t * 4 + q;
        c[q] = (n < N_NODES) ? cnt_unpack(cnt4[n * 4 + (oct >> 1)], oct & 1) : 0;
        sum += c[q];
    }
    s[t] = sum;
    __syncthreads();
    #pragma unroll
    for (int off = 1; off < 256; off <<= 1) {
        int u = (t >= off) ? s[t - off] : 0;
        __syncthreads();
        s[t] += u;
        __syncthreads();
    }
    int base = gbase[g];
    int run = base + s[t] - sum;
    #pragma unroll
    for (int q = 0; q < 4; ++q) {
        int n = tile * TS + t * 4 + q;
        if (n < N_NODES) { slotstart[n * 8 + oct] = run; run += c[q]; }
    }
    int cntg = s[255];
    int padded = ((cntg + 63) >> 6) << 6;
    for (int w = t; w < (padded >> 6); w += 256)
        winoct[(base >> 6) + w] = (unsigned char)oct;
    for (int i = t; i < padded - cntg; i += 256) {
        uint4 z; z.x = z.y = z.z = z.w = 0u;
        slotmeta[base + cntg + i] = z;
    }
}

// scatter + fused L1 message (do_msg: z = x[src] * sum_b wb*W1[idx_b,:])
__global__ __launch_bounds__(256) void scatter2_k(const int* __restrict__ src,
                                                  const int* __restrict__ dst,
                                                  const float* __restrict__ pseudo,
                                                  const unsigned short* __restrict__ rank16,
                                                  const int* __restrict__ slotstart,
                                                  uint4* __restrict__ slotmeta,
                                                  const float* __restrict__ x,
                                                  const float* __restrict__ W1,
                                                  __half* __restrict__ m1,
                                                  int do_msg) {
    int e = blockIdx.x * 256 + threadIdx.x;
    if (e >= N_EDGES) return;
    int d = dst[e];
    size_t pb = (size_t)e * 3;
    int oct; float fr0, fr1, fr2;
    pseudo_to_of(pseudo[pb], pseudo[pb + 1], pseudo[pb + 2], oct, fr0, fr1, fr2);
    int slot = slotstart[d * 8 + oct] + (int)rank16[e];
    int se = src[e];
    union { uint4 v; struct { int s; __half2 f01; __half2 f2x; unsigned pad; } t; } su;
    su.t.s   = se;
    su.t.f01 = __floats2half2_rn(fr0, fr1);
    su.t.f2x = __floats2half2_rn(fr2, 0.0f);
    su.t.pad = 0u;
    slotmeta[slot] = su.v;

    if (do_msg) {
        float a0[2] = {1.0f - fr0, fr0};
        float a1[2] = {1.0f - fr1, fr1};
        float a2[2] = {1.0f - fr2, fr2};
        const int bidx = (oct & 1) + 3 * ((oct >> 1) & 1) + 9 * ((oct >> 2) & 1);
        float z[8];
        #pragma unroll
        for (int o = 0; o < 8; ++o) z[o] = 0.0f;
        #pragma unroll
        for (int b = 0; b < 8; ++b) {
            float wb = a0[b & 1] * a1[(b >> 1) & 1] * a2[(b >> 2) & 1];
            int idx = bidx + (b & 1) + 3 * ((b >> 1) & 1) + 9 * ((b >> 2) & 1);
            const float* __restrict__ wp = W1 + idx * 8;
            #pragma unroll
            for (int o = 0; o < 8; ++o) z[o] = fmaf(wb, wp[o], z[o]);
        }
        float xs = x[se];
        #pragma unroll
        for (int o = 0; o < 8; ++o) z[o] *= xs;
        storeanyT<8>(m1 + (size_t)slot * 8, z);
    }
}

// ===================================================================
// W prep: fragment-ordered fp16 B tables, all 4 MFMA layers in one launch
// ===================================================================

template<int Fin, int Fout>
__device__ __forceinline__ void wprep_elem(const float* __restrict__ W,
                                           _Float16* __restrict__ WB, int i) {
    constexpr int KT = (8 * Fin) / 32;
    constexpr int NT = (Fout + 15) / 16;
    int j    = i & 7;
    int lane = (i >> 3) & 63;
    int rest = i >> 9;
    int nt = rest % NT; rest /= NT;
    int kt = rest % KT;
    int g  = rest / KT;
    int kb = lane >> 4, n = lane & 15;
    int k  = kt * 32 + kb * 8 + j;
    int b  = k / Fin, f = k % Fin;
    int bidx = (g & 1) + 3 * ((g >> 1) & 1) + 9 * ((g >> 2) & 1);
    int idx  = bidx + (b & 1) + 3 * ((b >> 1) & 1) + 9 * ((b >> 2) & 1);
    int col  = nt * 16 + n;
    float v = (col < Fout) ? W[((size_t)idx * Fin + f) * Fout + col] : 0.0f;
    WB[i] = (_Float16)v;
}

#define WS2 8192
#define WS3 32768
#define WS4 32768
#define WS5 16384

__global__ __launch_bounds__(256) void wprep_all_k(const float* __restrict__ W2,
                                                   const float* __restrict__ W3,
                                                   const float* __restrict__ W4,
                                                   const float* __restrict__ W5,
                                                   _Float16* __restrict__ WB2,
                                                   _Float16* __restrict__ WB3,
                                                   _Float16* __restrict__ WB4,
                                                   _Float16* __restrict__ WB5) {
    int i = blockIdx.x * 256 + threadIdx.x;
    if (i < WS2) { wprep_elem<8, 16>(W2, WB2, i); return; }
    i -= WS2;
    if (i < WS3) { wprep_elem<16, 32>(W3, WB3, i); return; }
    i -= WS3;
    if (i < WS4) { wprep_elem<32, 16>(W4, WB4, i); return; }
    i -= WS4;
    if (i < WS5) { wprep_elem<16, 8>(W5, WB5, i); return; }
}

// ===================================================================
// MFMA message kernel: direct-global A-operands, octant from winoct
// ===================================================================

template<int Fin, int Fout>
__global__ __launch_bounds__(256) void msg_mfma_k(const __half* __restrict__ h,
                                                  const uint4* __restrict__ slotmeta,
                                                  const unsigned char* __restrict__ winoct,
                                                  const int* __restrict__ tot,
                                                  const _Float16* __restrict__ WB,
                                                  __half* __restrict__ m) {
    constexpr int KT = (8 * Fin) / 32;
    constexpr int NT = (Fout + 15) / 16;
    constexpr int LOG2FIN = (Fin == 8) ? 3 : (Fin == 16) ? 4 : 5;
    constexpr int ZR = NT * 16 + 8;

    __shared__ __align__(16) _Float16 zbuf[4][64 * ZR];

    const int base = blockIdx.x * 256;
    if (base >= tot[1]) return;

    const int tid = threadIdx.x, wv = tid >> 6, lane = tid & 63;
    const int slot = base + tid;
    const int wbase = base + wv * 64;
    const int kb = lane >> 4;

    int oct = winoct[(base >> 6) + wv];
    oct = __builtin_amdgcn_readfirstlane(oct);

    int   sE[4];
    float g0[4], h0[4], g1[4], h1[4], g2[4], h2v[4];
    #pragma unroll
    for (int mt = 0; mt < 4; ++mt) {
        union { uint4 v; struct { int s; __half2 f01; __half2 f2x; unsigned pad; } t; } u;
        u.v = slotmeta[wbase + mt * 16 + (lane & 15)];
        sE[mt] = u.t.s;
        float2 f01 = __half22float2(u.t.f01);
        float2 f2x = __half22float2(u.t.f2x);
        g0[mt] = 1.0f - f01.x; h0[mt] = f01.x;
        g1[mt] = 1.0f - f01.y; h1[mt] = f01.y;
        g2[mt] = 1.0f - f2x.x; h2v[mt] = f2x.x;
    }

    f32x4 acc[4][NT];
    #pragma unroll
    for (int mt = 0; mt < 4; ++mt)
        #pragma unroll
        for (int nt = 0; nt < NT; ++nt)
            acc[mt][nt] = (f32x4){0.0f, 0.0f, 0.0f, 0.0f};

    const f16x8* __restrict__ WBv = (const f16x8*)WB;
    const f16x8* __restrict__ hv  = (const f16x8*)h;

    #pragma unroll
    for (int kt = 0; kt < KT; ++kt) {
        f16x8 bf[NT];
        #pragma unroll
        for (int nt = 0; nt < NT; ++nt)
            bf[nt] = WBv[((oct * KT + kt) * NT + nt) * 64 + lane];

        const int k0 = kt * 32 + kb * 8;
        const int b  = k0 >> LOG2FIN;
        const int f8 = (k0 & (Fin - 1)) >> 3;

        #pragma unroll
        for (int mt = 0; mt < 4; ++mt) {
            f16x8 xa = hv[(size_t)sE[mt] * (Fin / 8) + f8];
            float w = ((b & 1) ? h0[mt] : g0[mt])
                    * ((b & 2) ? h1[mt] : g1[mt])
                    * ((b & 4) ? h2v[mt] : g2[mt]);
            _Float16 wh = (_Float16)w;
            f16x8 av;
            #pragma unroll
            for (int j = 0; j < 8; ++j) av[j] = xa[j] * wh;
            #pragma unroll
            for (int nt = 0; nt < NT; ++nt)
                acc[mt][nt] = __builtin_amdgcn_mfma_f32_16x16x32_f16(av, bf[nt], acc[mt][nt], 0, 0, 0);
        }
    }

    #pragma unroll
    for (int mt = 0; mt < 4; ++mt) {
        #pragma unroll
        for (int nt = 0; nt < NT; ++nt) {
            #pragma unroll
            for (int q = 0; q < 4; ++q) {
                int e = mt * 16 + (lane >> 4) * 4 + q;
                int o = nt * 16 + (lane & 15);
                zbuf[wv][e * ZR + o] = (_Float16)acc[mt][nt][q];
            }
        }
    }
    __syncthreads();

    constexpr int NV = (Fout * 2) / 16;
    const uint4* zr = (const uint4*)&zbuf[wv][lane * ZR];
    uint4* mp = (uint4*)(m + (size_t)slot * Fout);
    #pragma unroll
    for (int r = 0; r < NV; ++r) mp[r] = zr[r];
}

// ===================================================================
// VALU msg kernel (L6 + fallback tiers)
// ===================================================================

template<int Fin, int Fout, int CH, typename TIn>
__global__ __launch_bounds__(256) void msg_k(const TIn* __restrict__ h,
                                             const uint4* __restrict__ slotmeta,
                                             const unsigned char* __restrict__ winoct,
                                             const int* __restrict__ tot,
                                             const float* __restrict__ W,
                                             __half* __restrict__ m,
                                             int coff) {
    int base = blockIdx.x * 256;
    if (base >= tot[1]) return;
    int wv = threadIdx.x >> 6;
    int g = winoct[(base >> 6) + wv];
    g = __builtin_amdgcn_readfirstlane(g);
    const int bidx = (g & 1) + 3 * ((g >> 1) & 1) + 9 * ((g >> 2) & 1);

    int j = base + threadIdx.x;

    union { uint4 v; struct { int s; __half2 f01; __half2 f2x; unsigned pad; } t; } u;
    u.v = slotmeta[j];
    int s = u.t.s;
    float2 f01 = __half22float2(u.t.f01);
    float2 f2x = __half22float2(u.t.f2x);
    float fr0 = f01.x, fr1 = f01.y, fr2 = f2x.x;
    float a0[2] = {1.0f - fr0, fr0};
    float a1[2] = {1.0f - fr1, fr1};
    float a2[2] = {1.0f - fr2, fr2};
    float w[8];
    #pragma unroll
    for (int b = 0; b < 8; ++b)
        w[b] = a0[b & 1] * a1[(b >> 1) & 1] * a2[(b >> 2) & 1];

    float x[Fin];
    loadanyT<Fin>(h + (size_t)s * Fin, x);

    float z[CH];
    #pragma unroll
    for (int o = 0; o < CH; ++o) z[o] = 0.0f;

    #pragma unroll
    for (int b = 0; b < 8; ++b) {
        const int idx = bidx + (b & 1) + 3 * ((b >> 1) & 1) + 9 * ((b >> 2) & 1);
        const float* __restrict__ wp = W + (size_t)idx * (Fin * Fout) + coff;
        float wb = w[b];
        #pragma unroll
        for (int f = 0; f < Fin; ++f) {
            float a = wb * x[f];
            #pragma unroll
            for (int o = 0; o < CH; ++o) z[o] = fmaf(a, wp[f * Fout + o], z[o]);
        }
    }

    storeanyT<CH>(m + (size_t)j * CH, z);
}

// ===================================================================
// gather kernel: 8 contiguous runs per node + root + bias + ELU
// ===================================================================

template<int Fin, int Fout, int CH, typename TIn, typename TOut>
__global__ __launch_bounds__(256) void gather_k(const TIn* __restrict__ hin,
                                                const __half* __restrict__ m,
                                                const int* __restrict__ slotstart,
                                                const unsigned* __restrict__ cnt4,
                                                const float* __restrict__ root,
                                                const float* __restrict__ bias,
                                                TOut* __restrict__ hout,
                                                int coff) {
    int n = blockIdx.x * 256 + threadIdx.x;
    if (n >= N_NODES) return;

    float acc[CH];
    #pragma unroll
    for (int o = 0; o < CH; ++o) acc[o] = bias[coff + o];

    float x[Fin];
    loadanyT<Fin>(hin + (size_t)n * Fin, x);
    #pragma unroll
    for (int f = 0; f < Fin; ++f) {
        #pragma unroll
        for (int o = 0; o < CH; ++o)
            acc[o] = fmaf(x[f], root[f * Fout + coff + o], acc[o]);
    }

    int4 sa = ((const int4*)slotstart)[n * 2];
    int4 sb = ((const int4*)slotstart)[n * 2 + 1];
    uint4 cp = ((const uint4*)cnt4)[n];
    int ss[8] = {sa.x, sa.y, sa.z, sa.w, sb.x, sb.y, sb.z, sb.w};
    int cc[8];
    cc[0] = (int)(cp.x & 0xFFFFu); cc[1] = (int)(cp.x >> 16);
    cc[2] = (int)(cp.y & 0xFFFFu); cc[3] = (int)(cp.y >> 16);
    cc[4] = (int)(cp.z & 0xFFFFu); cc[5] = (int)(cp.z >> 16);
    cc[6] = (int)(cp.w & 0xFFFFu); cc[7] = (int)(cp.w >> 16);

    #pragma unroll
    for (int oct = 0; oct < 8; ++oct) {
        int p = ss[oct];
        for (int j = 0; j < cc[oct]; ++j)
            accum_m_f16<CH>(acc, m + (size_t)(p + j) * CH);
    }

    float zz[CH];
    #pragma unroll
    for (int o = 0; o < CH; ++o) {
        float t = acc[o];
        zz[o] = t > 0.0f ? t : expm1f(t);
    }
    storeanyT<CH>(hout + (size_t)n * Fout + coff, zz);
}

// ===================================================================
// FALLBACK PATH (atomic, fp32) — only if workspace is tiny
// ===================================================================

template<int Fin, int Fout>
__global__ __launch_bounds__(256) void init_out_k(const float* __restrict__ h,
                                                  const float* __restrict__ root,
                                                  const float* __restrict__ bias,
                                                  float* __restrict__ out) {
    int n = blockIdx.x * 256 + threadIdx.x;
    if (n >= N_NODES) return;
    float xr[Fin];
    #pragma unroll
    for (int f = 0; f < Fin; ++f) xr[f] = h[(size_t)n * Fin + f];
    float z[Fout];
    #pragma unroll
    for (int o = 0; o < Fout; ++o) z[o] = bias[o];
    #pragma unroll
    for (int f = 0; f < Fin; ++f)
        #pragma unroll
        for (int o = 0; o < Fout; ++o) z[o] += xr[f] * root[f * Fout + o];
    #pragma unroll
    for (int o = 0; o < Fout; ++o) out[(size_t)n * Fout + o] = z[o];
}

template<int Fin, int Fout>
__global__ __launch_bounds__(256) void edge_k(const float* __restrict__ h,
                                              const int* __restrict__ src,
                                              const int* __restrict__ dst,
                                              const float* __restrict__ pseudo,
                                              const float* __restrict__ W,
                                              float* __restrict__ out) {
    constexpr int KFF = Fin * Fout;
    constexpr int STRIDE = KFF + 1;
    __shared__ float sW[27 * STRIDE];
    for (int i = threadIdx.x; i < 27 * KFF; i += 256) {
        int k = i / KFF;
        sW[k * STRIDE + (i - k * KFF)] = W[i];
    }
    __syncthreads();
    int e = blockIdx.x * 256 + threadIdx.x;
    if (e >= N_EDGES) return;
    int s = src[e], d = dst[e];
    size_t pb = (size_t)e * 3;
    int oct; float fr0, fr1, fr2;
    pseudo_to_of(pseudo[pb], pseudo[pb+1], pseudo[pb+2], oct, fr0, fr1, fr2);
    int i0 = oct & 1, i1 = (oct >> 1) & 1, i2 = (oct >> 2) & 1;
    float a0[2] = {1.0f - fr0, fr0};
    float a1[2] = {1.0f - fr1, fr1};
    float a2[2] = {1.0f - fr2, fr2};
    float xr[Fin];
    #pragma unroll
    for (int f = 0; f < Fin; ++f) xr[f] = h[(size_t)s * Fin + f];
    float z[Fout];
    #pragma unroll
    for (int o = 0; o < Fout; ++o) z[o] = 0.0f;
    #pragma unroll
    for (int b = 0; b < 8; ++b) {
        int idx = (i0 + (b & 1)) + 3 * (i1 + ((b >> 1) & 1)) + 9 * (i2 + ((b >> 2) & 1));
        float wb = a0[b & 1] * a1[(b >> 1) & 1] * a2[(b >> 2) & 1];
        const float* wp = &sW[idx * STRIDE];
        #pragma unroll
        for (int f = 0; f < Fin; ++f) {
            float a = wb * xr[f];
            #pragma unroll
            for (int o = 0; o < Fout; ++o) z[o] += a * wp[f * Fout + o];
        }
    }
    float* op = out + (size_t)d * Fout;
    #pragma unroll
    for (int o = 0; o < Fout; ++o) atomicAdd(&op[o], z[o]);
}

__global__ __launch_bounds__(256) void elu_k(float* __restrict__ p, int total) {
    int i = blockIdx.x * 256 + threadIdx.x;
    if (i < total) {
        float t = p[i];
        p[i] = t > 0.0f ? t : expm1f(t);
    }
}

// ===================================================================
// host
// ===================================================================

template<int Fin, int Fout, typename TIn, typename TOut>
static void run_layer_mfma(const TIn* hin, TOut* hout,
                           const float* root, const float* bias,
                           const uint4* slotmeta, const unsigned char* winoct,
                           const int* tot, const int* slotstart, const unsigned* cnt4,
                           const _Float16* WB, __half* m, hipStream_t stream) {
    msg_mfma_k<Fin, Fout><<<GRID_E2, 256, 0, stream>>>(hin, slotmeta, winoct, tot, WB, m);
    gather_k<Fin, Fout, Fout, TIn, TOut><<<(N_NODES + 255) / 256, 256, 0, stream>>>(
        hin, m, slotstart, cnt4, root, bias, hout, 0);
}

template<int Fin, int Fout, typename TIn, typename TOut>
static void run_layer_valu(const TIn* hin, TOut* hout,
                           const float* W, const float* root, const float* bias,
                           const uint4* slotmeta, const unsigned char* winoct,
                           const int* tot, const int* slotstart, const unsigned* cnt4,
                           __half* m, int chunk, hipStream_t stream) {
    const int GN = (N_NODES + 255) / 256;
    if (Fout <= chunk) {
        msg_k<Fin, Fout, Fout, TIn><<<GRID_E2, 256, 0, stream>>>(hin, slotmeta, winoct, tot, W, m, 0);
        gather_k<Fin, Fout, Fout, TIn, TOut><<<GN, 256, 0, stream>>>(hin, m, slotstart, cnt4, root, bias, hout, 0);
        return;
    }
    if constexpr (Fout > 16) {
        if (chunk == 16) {
            for (int p = 0; p < Fout / 16; ++p) {
                msg_k<Fin, Fout, 16, TIn><<<GRID_E2, 256, 0, stream>>>(hin, slotmeta, winoct, tot, W, m, 16 * p);
                gather_k<Fin, Fout, 16, TIn, TOut><<<GN, 256, 0, stream>>>(hin, m, slotstart, cnt4, root, bias, hout, 16 * p);
            }
            return;
        }
    }
    if constexpr (Fout > 8) {
        if (chunk == 8) {
            for (int p = 0; p < Fout / 8; ++p) {
                msg_k<Fin, Fout, 8, TIn><<<GRID_E2, 256, 0, stream>>>(hin, slotmeta, winoct, tot, W, m, 8 * p);
                gather_k<Fin, Fout, 8, TIn, TOut><<<GN, 256, 0, stream>>>(hin, m, slotstart, cnt4, root, bias, hout, 8 * p);
            }
            return;
        }
    }
    if constexpr (Fout > 4) {
        if (chunk == 4) {
            for (int p = 0; p < Fout / 4; ++p) {
                msg_k<Fin, Fout, 4, TIn><<<GRID_E2, 256, 0, stream>>>(hin, slotmeta, winoct, tot, W, m, 4 * p);
                gather_k<Fin, Fout, 4, TIn, TOut><<<GN, 256, 0, stream>>>(hin, m, slotstart, cnt4, root, bias, hout, 4 * p);
            }
            return;
        }
    }
    if constexpr (Fout > 2) {
        if (chunk == 2) {
            for (int p = 0; p < Fout / 2; ++p) {
                msg_k<Fin, Fout, 2, TIn><<<GRID_E2, 256, 0, stream>>>(hin, slotmeta, winoct, tot, W, m, 2 * p);
                gather_k<Fin, Fout, 2, TIn, TOut><<<GN, 256, 0, stream>>>(hin, m, slotstart, cnt4, root, bias, hout, 2 * p);
            }
            return;
        }
    }
}

template<int Fin, int Fout>
static void run_layer_old(const float* hin, float* hout,
                          const float* W, const float* root, const float* bias,
                          const int* src, const int* dst, const float* pseudo,
                          hipStream_t stream) {
    init_out_k<Fin, Fout><<<(N_NODES + 255) / 256, 256, 0, stream>>>(hin, root, bias, hout);
    edge_k<Fin, Fout><<<(N_EDGES + 255) / 256, 256, 0, stream>>>(hin, src, dst, pseudo, W, hout);
    int total = N_NODES * Fout;
    elu_k<<<(total + 255) / 256, 256, 0, stream>>>(hout, total);
}

extern "C" void kernel_launch(void* const* d_in, const int* in_sizes, int n_in,
                              void* d_out, int out_size, void* d_ws, size_t ws_size,
                              hipStream_t stream) {
    const float* x      = (const float*)d_in[0];
    const int*   ei     = (const int*)d_in[1];
    const float* pseudo = (const float*)d_in[2];
    const int* src = ei;
    const int* dst = ei + N_EDGES;

    const float* W[6]; const float* R[6]; const float* B[6];
    for (int i = 0; i < 6; ++i) {
        W[i] = (const float*)d_in[3 + 3 * i];
        R[i] = (const float*)d_in[4 + 3 * i];
        B[i] = (const float*)d_in[5 + 3 * i];
    }
    float* out = (float*)d_out;
    char* ws = (char*)d_ws;

    // ---- pick the largest output-chunk whose workspace fits ----
    const int tiers[5] = {32, 16, 8, 4, 2};
    int chunk = 0;
    size_t o_hA = 0, o_hB = 0, o_c4 = 0, o_ss = 0, o_rk = 0, o_meta = 0,
           o_wo = 0, o_sm = 0, o_wb = 0, o_m = 0;
    for (int t = 0; t < 5; ++t) {
        int c = tiers[t];
        size_t off = 0;
        auto alloc = [&](size_t bytes) { size_t cur = off; off = (off + bytes + 255) & ~(size_t)255; return cur; };
        size_t a_hA   = alloc((size_t)N_NODES * 32 * 2);        // fp16 activations
        size_t a_hB   = alloc((size_t)N_NODES * 32 * 2);
        size_t a_c4   = alloc((size_t)N_NODES * 4 * 4);         // packed 16-bit counters
        size_t a_ss   = alloc((size_t)N_NODES * 8 * 4);
        size_t a_rk   = alloc((size_t)N_EDGES * 2);
        size_t a_meta = alloc((size_t)(2 * NGRP + 8) * 4);
        size_t a_wo   = alloc((size_t)(E_PAD2 / 64));
        size_t a_sm   = alloc((size_t)E_PAD2 * 16);
        size_t a_wb   = alloc((size_t)4 * 65536 * 2);
        size_t a_m    = alloc((size_t)E_PAD2 * c * 2);
        if (off <= ws_size) {
            chunk = c;
            o_hA = a_hA; o_hB = a_hB; o_c4 = a_c4; o_ss = a_ss; o_rk = a_rk;
            o_meta = a_meta; o_wo = a_wo; o_sm = a_sm; o_wb = a_wb; o_m = a_m;
            break;
        }
    }

    if (chunk > 0) {
        __half* hA     = (__half*)(ws + o_hA);
        __half* hB     = (__half*)(ws + o_hB);
        unsigned* cnt4 = (unsigned*)(ws + o_c4);
        int*   slotst  = (int*)(ws + o_ss);
        unsigned short* rank16 = (unsigned short*)(ws + o_rk);
        int*   gsum    = (int*)(ws + o_meta);
        int*   gbase   = gsum + NGRP;
        int*   tot     = gbase + NGRP;
        unsigned char* winoct = (unsigned char*)(ws + o_wo);
        uint4* slotmeta= (uint4*)(ws + o_sm);
        _Float16* WB2  = (_Float16*)(ws + o_wb);
        _Float16* WB3  = WB2 + 65536;
        _Float16* WB4  = WB2 + 2 * 65536;
        _Float16* WB5  = WB2 + 3 * 65536;
        __half* m      = (__half*)(ws + o_m);

        const int fuse_l1 = (chunk >= 8) ? 1 : 0;

        hipMemsetAsync(cnt4, 0, (size_t)N_NODES * 4 * 4, stream);

        count8_k<<<N_EDGES / 256, 256, 0, stream>>>(dst, pseudo, cnt4, rank16);
        scan_g1<<<NGRP, 256, 0, stream>>>(cnt4, gsum);
        scan_g2<<<1, 1024, 0, stream>>>(gsum, gbase, tot, winoct, slotmeta);
        scan_g3<<<NGRP, 256, 0, stream>>>(cnt4, gbase, slotst, winoct, slotmeta);
        scatter2_k<<<N_EDGES / 256, 256, 0, stream>>>(src, dst, pseudo, rank16, slotst, slotmeta,
                                                      x, W[0], m, fuse_l1);

        const int GN = (N_NODES + 255) / 256;

        if (chunk == 32) {
            wprep_all_k<<<(WS2 + WS3 + WS4 + WS5 + 255) / 256, 256, 0, stream>>>(
                W[1], W[2], W[3], W[4], WB2, WB3, WB4, WB5);

            // L1: message already produced by scatter2 -> gather only
            gather_k<1, 8, 8, float, __half><<<GN, 256, 0, stream>>>(
                x, m, slotst, cnt4, R[0], B[0], hA, 0);

            run_layer_mfma<8, 16, __half, __half>(hA, hB, R[1], B[1], slotmeta, winoct, tot,
                                                  slotst, cnt4, WB2, m, stream);
            run_layer_mfma<16, 32, __half, __half>(hB, hA, R[2], B[2], slotmeta, winoct, tot,
                                                   slotst, cnt4, WB3, m, stream);
            run_layer_mfma<32, 16, __half, __half>(hA, hB, R[3], B[3], slotmeta, winoct, tot,
                                                   slotst, cnt4, WB4, m, stream);
            run_layer_mfma<16, 8, __half, __half>(hB, hA, R[4], B[4], slotmeta, winoct, tot,
                                                  slotst, cnt4, WB5, m, stream);
            run_layer_valu<8, 1, __half, float>(hA, out, W[5], R[5], B[5], slotmeta, winoct, tot,
                                                slotst, cnt4, m, chunk, stream);
        } else {
            if (fuse_l1) {
                gather_k<1, 8, 8, float, __half><<<GN, 256, 0, stream>>>(
                    x, m, slotst, cnt4, R[0], B[0], hA, 0);
            } else {
                run_layer_valu<1, 8, float, __half>(x, hA, W[0], R[0], B[0], slotmeta, winoct, tot,
                                                    slotst, cnt4, m, chunk, stream);
            }
            run_layer_valu<8, 16, __half, __half>(hA, hB, W[1], R[1], B[1], slotmeta, winoct, tot,
                                                  slotst, cnt4, m, chunk, stream);
            run_layer_valu<16, 32, __half, __half>(hB, hA, W[2], R[2], B[2], slotmeta, winoct, tot,
                                                   slotst, cnt4, m, chunk, stream);
            run_layer_valu<32, 16, __half, __half>(hA, hB, W[3], R[3], B[3], slotmeta, winoct, tot,
                                                   slotst, cnt4, m, chunk, stream);
            run_layer_valu<16, 8, __half, __half>(hB, hA, W[4], R[4], B[4], slotmeta, winoct, tot,
                                                  slotst, cnt4, m, chunk, stream);
            run_layer_valu<8, 1, __half, float>(hA, out, W[5], R[5], B[5], slotmeta, winoct, tot,
                                                slotst, cnt4, m, chunk, stream);
        }
    } else {
        float* hAf = (float*)ws;
        float* hBf = hAf + (size_t)N_NODES * 32;
        run_layer_old<1, 8>  (x,   hAf, W[0], R[0], B[0], src, dst, pseudo, stream);
        run_layer_old<8, 16> (hAf, hBf, W[1], R[1], B[1], src, dst, pseudo, stream);
        run_layer_old<16, 32>(hBf, hAf, W[2], R[2], B[2], src, dst, pseudo, stream);
        run_layer_old<32, 16>(hAf, hBf, W[3], R[3], B[3], src, dst, pseudo, stream);
        run_layer_old<16, 8> (hBf, hAf, W[4], R[4], B[4], src, dst, pseudo, stream);
        run_layer_old<8, 1>  (hAf, out, W[5], R[5], B[5], src, dst, pseudo, stream);
    }
}

// Round 14
// 396.925 us; speedup vs baseline: 2.8192x; 1.0318x over previous
//
#include <hip/hip_runtime.h>
#include <hip/hip_fp16.h>

#define N_NODES 100000
#define N_EDGES 1600000
#define TS      1024
#define NTILE   ((N_NODES + TS - 1) / TS)            // 98
#define NGRP    (NTILE * 8)                          // 784 (tile, octant) groups
#define E_PAD2  (N_EDGES + NGRP * 64 + 256)          // padded slot capacity
#define GRID_E2 (E_PAD2 / 256)

typedef _Float16 f16x8 __attribute__((ext_vector_type(8)));
typedef float    f32x4 __attribute__((ext_vector_type(4)));

// ===================================================================
// helpers
// ===================================================================

__device__ __forceinline__ void pseudo_to_of(float p0, float p1, float p2,
                                             int& oct, float& fr0, float& fr1, float& fr2) {
    float v0 = p0 * 2.0f, v1 = p1 * 2.0f, v2 = p2 * 2.0f;
    int i0 = v0 >= 1.0f, i1 = v1 >= 1.0f, i2 = v2 >= 1.0f;
    fr0 = v0 - (float)i0; fr1 = v1 - (float)i1; fr2 = v2 - (float)i2;
    oct = i0 + 2 * i1 + 4 * i2;
}

template<int Fin>
__device__ __forceinline__ void loadanyT(const float* __restrict__ hp, float* x) {
    if constexpr (Fin % 4 == 0) {
        const float4* xv = reinterpret_cast<const float4*>(hp);
        #pragma unroll
        for (int f = 0; f < Fin / 4; ++f) {
            float4 t = xv[f];
            x[4*f+0] = t.x; x[4*f+1] = t.y; x[4*f+2] = t.z; x[4*f+3] = t.w;
        }
    } else {
        #pragma unroll
        for (int f = 0; f < Fin; ++f) x[f] = hp[f];
    }
}

template<int Fin>
__device__ __forceinline__ void loadanyT(const __half* __restrict__ hp, float* x) {
    if constexpr (Fin % 8 == 0) {
        #pragma unroll
        for (int r = 0; r < Fin / 8; ++r) {
            union { uint4 v; __half2 h2[4]; } u;
            u.v = ((const uint4*)hp)[r];
            #pragma unroll
            for (int q = 0; q < 4; ++q) {
                float2 f = __half22float2(u.h2[q]);
                x[r*8 + 2*q]     = f.x;
                x[r*8 + 2*q + 1] = f.y;
            }
        }
    } else {
        #pragma unroll
        for (int f = 0; f < Fin; ++f) x[f] = __half2float(hp[f]);
    }
}

template<int CH>
__device__ __forceinline__ void storeanyT(float* __restrict__ p, const float* z) {
    if constexpr (CH % 4 == 0) {
        #pragma unroll
        for (int o = 0; o < CH / 4; ++o) {
            float4 t; t.x = z[4*o]; t.y = z[4*o+1]; t.z = z[4*o+2]; t.w = z[4*o+3];
            ((float4*)p)[o] = t;
        }
    } else if constexpr (CH % 2 == 0) {
        #pragma unroll
        for (int o = 0; o < CH / 2; ++o) {
            float2 t; t.x = z[2*o]; t.y = z[2*o+1];
            ((float2*)p)[o] = t;
        }
    } else {
        #pragma unroll
        for (int o = 0; o < CH; ++o) p[o] = z[o];
    }
}

template<int CH>
__device__ __forceinline__ void storeanyT(__half* __restrict__ p, const float* z) {
    if constexpr (CH % 8 == 0) {
        #pragma unroll
        for (int q = 0; q < CH / 8; ++q) {
            union { uint4 v; __half2 h2[4]; } u;
            #pragma unroll
            for (int r = 0; r < 4; ++r)
                u.h2[r] = __floats2half2_rn(z[q*8 + 2*r], z[q*8 + 2*r + 1]);
            ((uint4*)p)[q] = u.v;
        }
    } else if constexpr (CH % 4 == 0) {
        #pragma unroll
        for (int q = 0; q < CH / 4; ++q) {
            union { uint2 v; __half2 h2[2]; } u;
            u.h2[0] = __floats2half2_rn(z[4*q],     z[4*q + 1]);
            u.h2[1] = __floats2half2_rn(z[4*q + 2], z[4*q + 3]);
            ((uint2*)p)[q] = u.v;
        }
    } else if constexpr (CH % 2 == 0) {
        #pragma unroll
        for (int q = 0; q < CH / 2; ++q)
            ((__half2*)p)[q] = __floats2half2_rn(z[2*q], z[2*q+1]);
    } else {
        #pragma unroll
        for (int o = 0; o < CH; ++o) p[o] = __float2half(z[o]);
    }
}

template<int CH>
__device__ __forceinline__ void accum_m_f16(float* acc, const __half* __restrict__ p) {
    if constexpr (CH % 8 == 0) {
        #pragma unroll
        for (int q = 0; q < CH / 8; ++q) {
            union { uint4 v; __half2 h2[4]; } u;
            u.v = ((const uint4*)p)[q];
            #pragma unroll
            for (int r = 0; r < 4; ++r) {
                float2 f = __half22float2(u.h2[r]);
                acc[q*8 + 2*r]     += f.x;
                acc[q*8 + 2*r + 1] += f.y;
            }
        }
    } else if constexpr (CH % 2 == 0) {
        #pragma unroll
        for (int q = 0; q < CH / 2; ++q) {
            float2 f = __half22float2(((const __half2*)p)[q]);
            acc[2*q] += f.x; acc[2*q+1] += f.y;
        }
    } else {
        #pragma unroll
        for (int o = 0; o < CH; ++o) acc[o] += __half2float(p[o]);
    }
}

__device__ __forceinline__ int cnt_unpack(unsigned v, int half) {
    return (int)((v >> (half * 16)) & 0xFFFFu);
}

// ===================================================================
// setup: (tile, octant, dst)-sorted slots; 16-bit packed counters
// ===================================================================

__global__ __launch_bounds__(256) void count8_k(const int* __restrict__ dst,
                                                const float* __restrict__ pseudo,
                                                unsigned* __restrict__ cnt4,
                                                unsigned short* __restrict__ rank16) {
    int e = blockIdx.x * 256 + threadIdx.x;
    if (e >= N_EDGES) return;
    int d = dst[e];
    size_t pb = (size_t)e * 3;
    int oct; float a, b, c;
    pseudo_to_of(pseudo[pb], pseudo[pb + 1], pseudo[pb + 2], oct, a, b, c);
    unsigned inc = 1u << ((oct & 1) * 16);
    unsigned r = atomicAdd(&cnt4[d * 4 + (oct >> 1)], inc);
    rank16[e] = (unsigned short)cnt_unpack(r, oct & 1);
}

__global__ __launch_bounds__(256) void scan_g1(const unsigned* __restrict__ cnt4,
                                               int* __restrict__ gsum) {
    __shared__ int red[256];
    int g = blockIdx.x, t = threadIdx.x;
    int tile = g >> 3, oct = g & 7;
    int s = 0;
    #pragma unroll
    for (int q = 0; q < 4; ++q) {
        int n = tile * TS + t * 4 + q;
        if (n < N_NODES) s += cnt_unpack(cnt4[n * 4 + (oct >> 1)], oct & 1);
    }
    red[t] = s;
    __syncthreads();
    #pragma unroll
    for (int off = 128; off > 0; off >>= 1) {
        if (t < off) red[t] += red[t + off];
        __syncthreads();
    }
    if (t == 0) gsum[g] = red[0];
}

__global__ __launch_bounds__(1024) void scan_g2(const int* __restrict__ gsum,
                                                int* __restrict__ gbase,
                                                int* __restrict__ tot,
                                                unsigned char* __restrict__ winoct,
                                                uint4* __restrict__ slotmeta) {
    __shared__ int s[1024];
    __shared__ int sraw;
    int t = threadIdx.x;
    int v = 0;
    if (t < NGRP) v = ((gsum[t] + 63) >> 6) << 6;
    s[t] = v;
    __syncthreads();
    #pragma unroll
    for (int off = 1; off < 1024; off <<= 1) {
        int u = (t >= off) ? s[t - off] : 0;
        __syncthreads();
        s[t] += u;
        __syncthreads();
    }
    if (t < NGRP) gbase[t] = s[t] - v;
    if (t == NGRP - 1) sraw = s[t];
    __syncthreads();
    int raw = sraw;
    int totp = (raw + 255) & ~255;
    if (t == 0) { tot[0] = raw; tot[1] = totp; }
    int fill = totp - raw;
    if (t < fill) {
        uint4 z; z.x = z.y = z.z = z.w = 0u;
        slotmeta[raw + t] = z;
    }
    if (t < (fill >> 6)) winoct[(raw >> 6) + t] = 0;
}

__global__ __launch_bounds__(256) void scan_g3(const unsigned* __restrict__ cnt4,
                                               const int* __restrict__ gbase,
                                               int* __restrict__ slotstart,
                                               unsigned char* __restrict__ winoct,
                                               uint4* __restrict__ slotmeta) {
    __shared__ int s[256];
    int g = blockIdx.x, t = threadIdx.x;
    int tile = g >> 3, oct = g & 7;
    int c[4];
    int sum = 0;
    #pragma unroll
    for (int q = 0; q < 4; ++q) {
        int n = tile * TS + t * 4 + q;
        c[q] = (n < N_NODES) ? cnt_unpack(cnt4[n * 4 + (oct >> 1)], oct & 1) : 0;
        sum += c[q];
    }
    s[t] = sum;
    __syncthreads();
    #pragma unroll
    for (int off = 1; off < 256; off <<= 1) {
        int u = (t >= off) ? s[t - off] : 0;
        __syncthreads();
        s[t] += u;
        __syncthreads();
    }
    int base = gbase[g];
    int run = base + s[t] - sum;
    #pragma unroll
    for (int q = 0; q < 4; ++q) {
        int n = tile * TS + t * 4 + q;
        if (n < N_NODES) { slotstart[n * 8 + oct] = run; run += c[q]; }
    }
    int cntg = s[255];
    int padded = ((cntg + 63) >> 6) << 6;
    for (int w = t; w < (padded >> 6); w += 256)
        winoct[(base >> 6) + w] = (unsigned char)oct;
    for (int i = t; i < padded - cntg; i += 256) {
        uint4 z; z.x = z.y = z.z = z.w = 0u;
        slotmeta[base + cntg + i] = z;
    }
}

__global__ __launch_bounds__(256) void scatter2_k(const int* __restrict__ src,
                                                  const int* __restrict__ dst,
                                                  const float* __restrict__ pseudo,
                                                  const unsigned short* __restrict__ rank16,
                                                  const int* __restrict__ slotstart,
                                                  uint4* __restrict__ slotmeta) {
    int e = blockIdx.x * 256 + threadIdx.x;
    if (e >= N_EDGES) return;
    int d = dst[e];
    size_t pb = (size_t)e * 3;
    int oct; float fr0, fr1, fr2;
    pseudo_to_of(pseudo[pb], pseudo[pb + 1], pseudo[pb + 2], oct, fr0, fr1, fr2);
    int slot = slotstart[d * 8 + oct] + (int)rank16[e];
    union { uint4 v; struct { int s; __half2 f01; __half2 f2x; unsigned pad; } t; } su;
    su.t.s   = src[e];
    su.t.f01 = __floats2half2_rn(fr0, fr1);
    su.t.f2x = __floats2half2_rn(fr2, 0.0f);
    su.t.pad = 0u;
    slotmeta[slot] = su.v;
}

// ===================================================================
// W prep: fragment-ordered fp16 B tables, all 4 MFMA layers in one launch
// ===================================================================

template<int Fin, int Fout>
__device__ __forceinline__ void wprep_elem(const float* __restrict__ W,
                                           _Float16* __restrict__ WB, int i) {
    constexpr int KT = (8 * Fin) / 32;
    constexpr int NT = (Fout + 15) / 16;
    int j    = i & 7;
    int lane = (i >> 3) & 63;
    int rest = i >> 9;
    int nt = rest % NT; rest /= NT;
    int kt = rest % KT;
    int g  = rest / KT;
    int kb = lane >> 4, n = lane & 15;
    int k  = kt * 32 + kb * 8 + j;
    int b  = k / Fin, f = k % Fin;
    int bidx = (g & 1) + 3 * ((g >> 1) & 1) + 9 * ((g >> 2) & 1);
    int idx  = bidx + (b & 1) + 3 * ((b >> 1) & 1) + 9 * ((b >> 2) & 1);
    int col  = nt * 16 + n;
    float v = (col < Fout) ? W[((size_t)idx * Fin + f) * Fout + col] : 0.0f;
    WB[i] = (_Float16)v;
}

#define WS2 8192
#define WS3 32768
#define WS4 32768
#define WS5 16384

__global__ __launch_bounds__(256) void wprep_all_k(const float* __restrict__ W2,
                                                   const float* __restrict__ W3,
                                                   const float* __restrict__ W4,
                                                   const float* __restrict__ W5,
                                                   _Float16* __restrict__ WB2,
                                                   _Float16* __restrict__ WB3,
                                                   _Float16* __restrict__ WB4,
                                                   _Float16* __restrict__ WB5) {
    int i = blockIdx.x * 256 + threadIdx.x;
    if (i < WS2) { wprep_elem<8, 16>(W2, WB2, i); return; }
    i -= WS2;
    if (i < WS3) { wprep_elem<16, 32>(W3, WB3, i); return; }
    i -= WS3;
    if (i < WS4) { wprep_elem<32, 16>(W4, WB4, i); return; }
    i -= WS4;
    if (i < WS5) { wprep_elem<16, 8>(W5, WB5, i); return; }
}

// ===================================================================
// MFMA message kernel: direct-global A-operands, octant from winoct
// ===================================================================

template<int Fin, int Fout>
__global__ __launch_bounds__(256) void msg_mfma_k(const __half* __restrict__ h,
                                                  const uint4* __restrict__ slotmeta,
                                                  const unsigned char* __restrict__ winoct,
                                                  const int* __restrict__ tot,
                                                  const _Float16* __restrict__ WB,
                                                  __half* __restrict__ m) {
    constexpr int KT = (8 * Fin) / 32;
    constexpr int NT = (Fout + 15) / 16;
    constexpr int LOG2FIN = (Fin == 8) ? 3 : (Fin == 16) ? 4 : 5;
    constexpr int ZR = NT * 16 + 8;

    __shared__ __align__(16) _Float16 zbuf[4][64 * ZR];

    const int base = blockIdx.x * 256;
    if (base >= tot[1]) return;

    const int tid = threadIdx.x, wv = tid >> 6, lane = tid & 63;
    const int slot = base + tid;
    const int wbase = base + wv * 64;
    const int kb = lane >> 4;

    int oct = winoct[(base >> 6) + wv];
    oct = __builtin_amdgcn_readfirstlane(oct);

    int   sE[4];
    float g0[4], h0[4], g1[4], h1[4], g2[4], h2v[4];
    #pragma unroll
    for (int mt = 0; mt < 4; ++mt) {
        union { uint4 v; struct { int s; __half2 f01; __half2 f2x; unsigned pad; } t; } u;
        u.v = slotmeta[wbase + mt * 16 + (lane & 15)];
        sE[mt] = u.t.s;
        float2 f01 = __half22float2(u.t.f01);
        float2 f2x = __half22float2(u.t.f2x);
        g0[mt] = 1.0f - f01.x; h0[mt] = f01.x;
        g1[mt] = 1.0f - f01.y; h1[mt] = f01.y;
        g2[mt] = 1.0f - f2x.x; h2v[mt] = f2x.x;
    }

    f32x4 acc[4][NT];
    #pragma unroll
    for (int mt = 0; mt < 4; ++mt)
        #pragma unroll
        for (int nt = 0; nt < NT; ++nt)
            acc[mt][nt] = (f32x4){0.0f, 0.0f, 0.0f, 0.0f};

    const f16x8* __restrict__ WBv = (const f16x8*)WB;
    const f16x8* __restrict__ hv  = (const f16x8*)h;

    #pragma unroll
    for (int kt = 0; kt < KT; ++kt) {
        f16x8 bf[NT];
        #pragma unroll
        for (int nt = 0; nt < NT; ++nt)
            bf[nt] = WBv[((oct * KT + kt) * NT + nt) * 64 + lane];

        const int k0 = kt * 32 + kb * 8;
        const int b  = k0 >> LOG2FIN;
        const int f8 = (k0 & (Fin - 1)) >> 3;

        #pragma unroll
        for (int mt = 0; mt < 4; ++mt) {
            f16x8 xa = hv[(size_t)sE[mt] * (Fin / 8) + f8];
            float w = ((b & 1) ? h0[mt] : g0[mt])
                    * ((b & 2) ? h1[mt] : g1[mt])
                    * ((b & 4) ? h2v[mt] : g2[mt]);
            _Float16 wh = (_Float16)w;
            f16x8 av;
            #pragma unroll
            for (int j = 0; j < 8; ++j) av[j] = xa[j] * wh;
            #pragma unroll
            for (int nt = 0; nt < NT; ++nt)
                acc[mt][nt] = __builtin_amdgcn_mfma_f32_16x16x32_f16(av, bf[nt], acc[mt][nt], 0, 0, 0);
        }
    }

    #pragma unroll
    for (int mt = 0; mt < 4; ++mt) {
        #pragma unroll
        for (int nt = 0; nt < NT; ++nt) {
            #pragma unroll
            for (int q = 0; q < 4; ++q) {
                int e = mt * 16 + (lane >> 4) * 4 + q;
                int o = nt * 16 + (lane & 15);
                zbuf[wv][e * ZR + o] = (_Float16)acc[mt][nt][q];
            }
        }
    }
    __syncthreads();

    constexpr int NV = (Fout * 2) / 16;
    const uint4* zr = (const uint4*)&zbuf[wv][lane * ZR];
    uint4* mp = (uint4*)(m + (size_t)slot * Fout);
    #pragma unroll
    for (int r = 0; r < NV; ++r) mp[r] = zr[r];
}

// ===================================================================
// VALU msg kernel (L1/L6 + fallback tiers)
// ===================================================================

template<int Fin, int Fout, int CH, typename TIn>
__global__ __launch_bounds__(256) void msg_k(const TIn* __restrict__ h,
                                             const uint4* __restrict__ slotmeta,
                                             const unsigned char* __restrict__ winoct,
                                             const int* __restrict__ tot,
                                             const float* __restrict__ W,
                                             __half* __restrict__ m,
                                             int coff) {
    int base = blockIdx.x * 256;
    if (base >= tot[1]) return;
    int wv = threadIdx.x >> 6;
    int g = winoct[(base >> 6) + wv];
    g = __builtin_amdgcn_readfirstlane(g);
    const int bidx = (g & 1) + 3 * ((g >> 1) & 1) + 9 * ((g >> 2) & 1);

    int j = base + threadIdx.x;

    union { uint4 v; struct { int s; __half2 f01; __half2 f2x; unsigned pad; } t; } u;
    u.v = slotmeta[j];
    int s = u.t.s;
    float2 f01 = __half22float2(u.t.f01);
    float2 f2x = __half22float2(u.t.f2x);
    float fr0 = f01.x, fr1 = f01.y, fr2 = f2x.x;
    float a0[2] = {1.0f - fr0, fr0};
    float a1[2] = {1.0f - fr1, fr1};
    float a2[2] = {1.0f - fr2, fr2};
    float w[8];
    #pragma unroll
    for (int b = 0; b < 8; ++b)
        w[b] = a0[b & 1] * a1[(b >> 1) & 1] * a2[(b >> 2) & 1];

    float x[Fin];
    loadanyT<Fin>(h + (size_t)s * Fin, x);

    float z[CH];
    #pragma unroll
    for (int o = 0; o < CH; ++o) z[o] = 0.0f;

    #pragma unroll
    for (int b = 0; b < 8; ++b) {
        const int idx = bidx + (b & 1) + 3 * ((b >> 1) & 1) + 9 * ((b >> 2) & 1);
        const float* __restrict__ wp = W + (size_t)idx * (Fin * Fout) + coff;
        float wb = w[b];
        #pragma unroll
        for (int f = 0; f < Fin; ++f) {
            float a = wb * x[f];
            #pragma unroll
            for (int o = 0; o < CH; ++o) z[o] = fmaf(a, wp[f * Fout + o], z[o]);
        }
    }

    storeanyT<CH>(m + (size_t)j * CH, z);
}

// ===================================================================
// gather kernel: 8 contiguous runs per node + root + bias + ELU
// ===================================================================

template<int Fin, int Fout, int CH, typename TIn, typename TOut>
__global__ __launch_bounds__(256) void gather_k(const TIn* __restrict__ hin,
                                                const __half* __restrict__ m,
                                                const int* __restrict__ slotstart,
                                                const unsigned* __restrict__ cnt4,
                                                const float* __restrict__ root,
                                                const float* __restrict__ bias,
                                                TOut* __restrict__ hout,
                                                int coff) {
    int n = blockIdx.x * 256 + threadIdx.x;
    if (n >= N_NODES) return;

    float acc[CH];
    #pragma unroll
    for (int o = 0; o < CH; ++o) acc[o] = bias[coff + o];

    float x[Fin];
    loadanyT<Fin>(hin + (size_t)n * Fin, x);
    #pragma unroll
    for (int f = 0; f < Fin; ++f) {
        #pragma unroll
        for (int o = 0; o < CH; ++o)
            acc[o] = fmaf(x[f], root[f * Fout + coff + o], acc[o]);
    }

    int4 sa = ((const int4*)slotstart)[n * 2];
    int4 sb = ((const int4*)slotstart)[n * 2 + 1];
    uint4 cp = ((const uint4*)cnt4)[n];
    int ss[8] = {sa.x, sa.y, sa.z, sa.w, sb.x, sb.y, sb.z, sb.w};
    int cc[8];
    cc[0] = (int)(cp.x & 0xFFFFu); cc[1] = (int)(cp.x >> 16);
    cc[2] = (int)(cp.y & 0xFFFFu); cc[3] = (int)(cp.y >> 16);
    cc[4] = (int)(cp.z & 0xFFFFu); cc[5] = (int)(cp.z >> 16);
    cc[6] = (int)(cp.w & 0xFFFFu); cc[7] = (int)(cp.w >> 16);

    #pragma unroll
    for (int oct = 0; oct < 8; ++oct) {
        int p = ss[oct];
        for (int j = 0; j < cc[oct]; ++j)
            accum_m_f16<CH>(acc, m + (size_t)(p + j) * CH);
    }

    float zz[CH];
    #pragma unroll
    for (int o = 0; o < CH; ++o) {
        float t = acc[o];
        zz[o] = t > 0.0f ? t : expm1f(t);
    }
    storeanyT<CH>(hout + (size_t)n * Fout + coff, zz);
}

// ===================================================================
// FALLBACK PATH (atomic, fp32) — only if workspace is tiny
// ===================================================================

template<int Fin, int Fout>
__global__ __launch_bounds__(256) void init_out_k(const float* __restrict__ h,
                                                  const float* __restrict__ root,
                                                  const float* __restrict__ bias,
                                                  float* __restrict__ out) {
    int n = blockIdx.x * 256 + threadIdx.x;
    if (n >= N_NODES) return;
    float xr[Fin];
    #pragma unroll
    for (int f = 0; f < Fin; ++f) xr[f] = h[(size_t)n * Fin + f];
    float z[Fout];
    #pragma unroll
    for (int o = 0; o < Fout; ++o) z[o] = bias[o];
    #pragma unroll
    for (int f = 0; f < Fin; ++f)
        #pragma unroll
        for (int o = 0; o < Fout; ++o) z[o] += xr[f] * root[f * Fout + o];
    #pragma unroll
    for (int o = 0; o < Fout; ++o) out[(size_t)n * Fout + o] = z[o];
}

template<int Fin, int Fout>
__global__ __launch_bounds__(256) void edge_k(const float* __restrict__ h,
                                              const int* __restrict__ src,
                                              const int* __restrict__ dst,
                                              const float* __restrict__ pseudo,
                                              const float* __restrict__ W,
                                              float* __restrict__ out) {
    constexpr int KFF = Fin * Fout;
    constexpr int STRIDE = KFF + 1;
    __shared__ float sW[27 * STRIDE];
    for (int i = threadIdx.x; i < 27 * KFF; i += 256) {
        int k = i / KFF;
        sW[k * STRIDE + (i - k * KFF)] = W[i];
    }
    __syncthreads();
    int e = blockIdx.x * 256 + threadIdx.x;
    if (e >= N_EDGES) return;
    int s = src[e], d = dst[e];
    size_t pb = (size_t)e * 3;
    int oct; float fr0, fr1, fr2;
    pseudo_to_of(pseudo[pb], pseudo[pb+1], pseudo[pb+2], oct, fr0, fr1, fr2);
    int i0 = oct & 1, i1 = (oct >> 1) & 1, i2 = (oct >> 2) & 1;
    float a0[2] = {1.0f - fr0, fr0};
    float a1[2] = {1.0f - fr1, fr1};
    float a2[2] = {1.0f - fr2, fr2};
    float xr[Fin];
    #pragma unroll
    for (int f = 0; f < Fin; ++f) xr[f] = h[(size_t)s * Fin + f];
    float z[Fout];
    #pragma unroll
    for (int o = 0; o < Fout; ++o) z[o] = 0.0f;
    #pragma unroll
    for (int b = 0; b < 8; ++b) {
        int idx = (i0 + (b & 1)) + 3 * (i1 + ((b >> 1) & 1)) + 9 * (i2 + ((b >> 2) & 1));
        float wb = a0[b & 1] * a1[(b >> 1) & 1] * a2[(b >> 2) & 1];
        const float* wp = &sW[idx * STRIDE];
        #pragma unroll
        for (int f = 0; f < Fin; ++f) {
            float a = wb * xr[f];
            #pragma unroll
            for (int o = 0; o < Fout; ++o) z[o] += a * wp[f * Fout + o];
        }
    }
    float* op = out + (size_t)d * Fout;
    #pragma unroll
    for (int o = 0; o < Fout; ++o) atomicAdd(&op[o], z[o]);
}

__global__ __launch_bounds__(256) void elu_k(float* __restrict__ p, int total) {
    int i = blockIdx.x * 256 + threadIdx.x;
    if (i < total) {
        float t = p[i];
        p[i] = t > 0.0f ? t : expm1f(t);
    }
}

// ===================================================================
// host
// ===================================================================

template<int Fin, int Fout, typename TIn, typename TOut>
static void run_layer_mfma(const TIn* hin, TOut* hout,
                           const float* root, const float* bias,
                           const uint4* slotmeta, const unsigned char* winoct,
                           const int* tot, const int* slotstart, const unsigned* cnt4,
                           const _Float16* WB, __half* m, hipStream_t stream) {
    msg_mfma_k<Fin, Fout><<<GRID_E2, 256, 0, stream>>>(hin, slotmeta, winoct, tot, WB, m);
    gather_k<Fin, Fout, Fout, TIn, TOut><<<(N_NODES + 255) / 256, 256, 0, stream>>>(
        hin, m, slotstart, cnt4, root, bias, hout, 0);
}

template<int Fin, int Fout, typename TIn, typename TOut>
static void run_layer_valu(const TIn* hin, TOut* hout,
                           const float* W, const float* root, const float* bias,
                           const uint4* slotmeta, const unsigned char* winoct,
                           const int* tot, const int* slotstart, const unsigned* cnt4,
                           __half* m, int chunk, hipStream_t stream) {
    const int GN = (N_NODES + 255) / 256;
    if (Fout <= chunk) {
        msg_k<Fin, Fout, Fout, TIn><<<GRID_E2, 256, 0, stream>>>(hin, slotmeta, winoct, tot, W, m, 0);
        gather_k<Fin, Fout, Fout, TIn, TOut><<<GN, 256, 0, stream>>>(hin, m, slotstart, cnt4, root, bias, hout, 0);
        return;
    }
    if constexpr (Fout > 16) {
        if (chunk == 16) {
            for (int p = 0; p < Fout / 16; ++p) {
                msg_k<Fin, Fout, 16, TIn><<<GRID_E2, 256, 0, stream>>>(hin, slotmeta, winoct, tot, W, m, 16 * p);
                gather_k<Fin, Fout, 16, TIn, TOut><<<GN, 256, 0, stream>>>(hin, m, slotstart, cnt4, root, bias, hout, 16 * p);
            }
            return;
        }
    }
    if constexpr (Fout > 8) {
        if (chunk == 8) {
            for (int p = 0; p < Fout / 8; ++p) {
                msg_k<Fin, Fout, 8, TIn><<<GRID_E2, 256, 0, stream>>>(hin, slotmeta, winoct, tot, W, m, 8 * p);
                gather_k<Fin, Fout, 8, TIn, TOut><<<GN, 256, 0, stream>>>(hin, m, slotstart, cnt4, root, bias, hout, 8 * p);
            }
            return;
        }
    }
    if constexpr (Fout > 4) {
        if (chunk == 4) {
            for (int p = 0; p < Fout / 4; ++p) {
                msg_k<Fin, Fout, 4, TIn><<<GRID_E2, 256, 0, stream>>>(hin, slotmeta, winoct, tot, W, m, 4 * p);
                gather_k<Fin, Fout, 4, TIn, TOut><<<GN, 256, 0, stream>>>(hin, m, slotstart, cnt4, root, bias, hout, 4 * p);
            }
            return;
        }
    }
    if constexpr (Fout > 2) {
        if (chunk == 2) {
            for (int p = 0; p < Fout / 2; ++p) {
                msg_k<Fin, Fout, 2, TIn><<<GRID_E2, 256, 0, stream>>>(hin, slotmeta, winoct, tot, W, m, 2 * p);
                gather_k<Fin, Fout, 2, TIn, TOut><<<GN, 256, 0, stream>>>(hin, m, slotstart, cnt4, root, bias, hout, 2 * p);
            }
            return;
        }
    }
}

template<int Fin, int Fout>
static void run_layer_old(const float* hin, float* hout,
                          const float* W, const float* root, const float* bias,
                          const int* src, const int* dst, const float* pseudo,
                          hipStream_t stream) {
    init_out_k<Fin, Fout><<<(N_NODES + 255) / 256, 256, 0, stream>>>(hin, root, bias, hout);
    edge_k<Fin, Fout><<<(N_EDGES + 255) / 256, 256, 0, stream>>>(hin, src, dst, pseudo, W, hout);
    int total = N_NODES * Fout;
    elu_k<<<(total + 255) / 256, 256, 0, stream>>>(hout, total);
}

extern "C" void kernel_launch(void* const* d_in, const int* in_sizes, int n_in,
                              void* d_out, int out_size, void* d_ws, size_t ws_size,
                              hipStream_t stream) {
    const float* x      = (const float*)d_in[0];
    const int*   ei     = (const int*)d_in[1];
    const float* pseudo = (const float*)d_in[2];
    const int* src = ei;
    const int* dst = ei + N_EDGES;

    const float* W[6]; const float* R[6]; const float* B[6];
    for (int i = 0; i < 6; ++i) {
        W[i] = (const float*)d_in[3 + 3 * i];
        R[i] = (const float*)d_in[4 + 3 * i];
        B[i] = (const float*)d_in[5 + 3 * i];
    }
    float* out = (float*)d_out;
    char* ws = (char*)d_ws;

    // ---- pick the largest output-chunk whose workspace fits ----
    const int tiers[5] = {32, 16, 8, 4, 2};
    int chunk = 0;
    size_t o_hA = 0, o_hB = 0, o_c4 = 0, o_ss = 0, o_rk = 0, o_meta = 0,
           o_wo = 0, o_sm = 0, o_wb = 0, o_m = 0;
    for (int t = 0; t < 5; ++t) {
        int c = tiers[t];
        size_t off = 0;
        auto alloc = [&](size_t bytes) { size_t cur = off; off = (off + bytes + 255) & ~(size_t)255; return cur; };
        size_t a_hA   = alloc((size_t)N_NODES * 32 * 2);        // fp16 activations
        size_t a_hB   = alloc((size_t)N_NODES * 32 * 2);
        size_t a_c4   = alloc((size_t)N_NODES * 4 * 4);         // packed 16-bit counters
        size_t a_ss   = alloc((size_t)N_NODES * 8 * 4);
        size_t a_rk   = alloc((size_t)N_EDGES * 2);
        size_t a_meta = alloc((size_t)(2 * NGRP + 8) * 4);
        size_t a_wo   = alloc((size_t)(E_PAD2 / 64));
        size_t a_sm   = alloc((size_t)E_PAD2 * 16);
        size_t a_wb   = alloc((size_t)4 * 65536 * 2);
        size_t a_m    = alloc((size_t)E_PAD2 * c * 2);
        if (off <= ws_size) {
            chunk = c;
            o_hA = a_hA; o_hB = a_hB; o_c4 = a_c4; o_ss = a_ss; o_rk = a_rk;
            o_meta = a_meta; o_wo = a_wo; o_sm = a_sm; o_wb = a_wb; o_m = a_m;
            break;
        }
    }

    if (chunk > 0) {
        __half* hA     = (__half*)(ws + o_hA);
        __half* hB     = (__half*)(ws + o_hB);
        unsigned* cnt4 = (unsigned*)(ws + o_c4);
        int*   slotst  = (int*)(ws + o_ss);
        unsigned short* rank16 = (unsigned short*)(ws + o_rk);
        int*   gsum    = (int*)(ws + o_meta);
        int*   gbase   = gsum + NGRP;
        int*   tot     = gbase + NGRP;
        unsigned char* winoct = (unsigned char*)(ws + o_wo);
        uint4* slotmeta= (uint4*)(ws + o_sm);
        _Float16* WB2  = (_Float16*)(ws + o_wb);
        _Float16* WB3  = WB2 + 65536;
        _Float16* WB4  = WB2 + 2 * 65536;
        _Float16* WB5  = WB2 + 3 * 65536;
        __half* m      = (__half*)(ws + o_m);

        hipMemsetAsync(cnt4, 0, (size_t)N_NODES * 4 * 4, stream);

        count8_k<<<N_EDGES / 256, 256, 0, stream>>>(dst, pseudo, cnt4, rank16);
        scan_g1<<<NGRP, 256, 0, stream>>>(cnt4, gsum);
        scan_g2<<<1, 1024, 0, stream>>>(gsum, gbase, tot, winoct, slotmeta);
        scan_g3<<<NGRP, 256, 0, stream>>>(cnt4, gbase, slotst, winoct, slotmeta);
        scatter2_k<<<N_EDGES / 256, 256, 0, stream>>>(src, dst, pseudo, rank16, slotst, slotmeta);

        if (chunk == 32) {
            wprep_all_k<<<(WS2 + WS3 + WS4 + WS5 + 255) / 256, 256, 0, stream>>>(
                W[1], W[2], W[3], W[4], WB2, WB3, WB4, WB5);

            run_layer_valu<1, 8, float, __half>(x, hA, W[0], R[0], B[0], slotmeta, winoct, tot,
                                                slotst, cnt4, m, chunk, stream);
            run_layer_mfma<8, 16, __half, __half>(hA, hB, R[1], B[1], slotmeta, winoct, tot,
                                                  slotst, cnt4, WB2, m, stream);
            run_layer_mfma<16, 32, __half, __half>(hB, hA, R[2], B[2], slotmeta, winoct, tot,
                                                   slotst, cnt4, WB3, m, stream);
            run_layer_mfma<32, 16, __half, __half>(hA, hB, R[3], B[3], slotmeta, winoct, tot,
                                                   slotst, cnt4, WB4, m, stream);
            run_layer_mfma<16, 8, __half, __half>(hB, hA, R[4], B[4], slotmeta, winoct, tot,
                                                  slotst, cnt4, WB5, m, stream);
            run_layer_valu<8, 1, __half, float>(hA, out, W[5], R[5], B[5], slotmeta, winoct, tot,
                                                slotst, cnt4, m, chunk, stream);
        } else {
            run_layer_valu<1, 8, float, __half>(x, hA, W[0], R[0], B[0], slotmeta, winoct, tot,
                                                slotst, cnt4, m, chunk, stream);
            run_layer_valu<8, 16, __half, __half>(hA, hB, W[1], R[1], B[1], slotmeta, winoct, tot,
                                                  slotst, cnt4, m, chunk, stream);
            run_layer_valu<16, 32, __half, __half>(hB, hA, W[2], R[2], B[2], slotmeta, winoct, tot,
                                                   slotst, cnt4, m, chunk, stream);
            run_layer_valu<32, 16, __half, __half>(hA, hB, W[3], R[3], B[3], slotmeta, winoct, tot,
                                                   slotst, cnt4, m, chunk, stream);
            run_layer_valu<16, 8, __half, __half>(hB, hA, W[4], R[4], B[4], slotmeta, winoct, tot,
                                                  slotst, cnt4, m, chunk, stream);
            run_layer_valu<8, 1, __half, float>(hA, out, W[5], R[5], B[5], slotmeta, winoct, tot,
                                                slotst, cnt4, m, chunk, stream);
        }
    } else {
        float* hAf = (float*)ws;
        float* hBf = hAf + (size_t)N_NODES * 32;
        run_layer_old<1, 8>  (x,   hAf, W[0], R[0], B[0], src, dst, pseudo, stream);
        run_layer_old<8, 16> (hAf, hBf, W[1], R[1], B[1], src, dst, pseudo, stream);
        run_layer_old<16, 32>(hBf, hAf, W[2], R[2], B[2], src, dst, pseudo, stream);
        run_layer_old<32, 16>(hAf, hBf, W[3], R[3], B[3], src, dst, pseudo, stream);
        run_layer_old<16, 8> (hBf, hAf, W[4], R[4], B[4], src, dst, pseudo, stream);
        run_layer_old<8, 1>  (hAf, out, W[5], R[5], B[5], src, dst, pseudo, stream);
    }
}